// Round 14
// baseline (1979.292 us; speedup 1.0000x reference)
//
#include <hip/hip_runtime.h>
#include <cstdint>
#include <cmath>

// Problem constants
static constexpr int BB = 16;    // batch
static constexpr int TT0 = 1024; // initial tokens
static constexpr int CC = 256;   // channels
static constexpr int EE = 512;   // embedding

typedef __bf16 bf16x8 __attribute__((ext_vector_type(8)));
typedef float  f32x4  __attribute__((ext_vector_type(4)));

// ---------------------------------------------------------------------------
// FPS body v6: one 64-lane wave per batch, ALL state in registers.
//  - per-j tracking: strict (nd > best) keeps FIRST j within lane (exact,
//    verified r10); coords bx/by/bz tracked via cndmask
//  - cross-lane max: DPP row_ror reduce + readlane cross-row (verified r12)
//  - index/coords recovery: ballot(best==gm) + ffs -> SGPR lane, then
//    v_readlane (SGPR selector, no ds_bpermute -- v3's mistake avoided)
// Lane-major index order + lowest-set-lane => exact jnp.argmax ties.
// Distance math bit-identical to reference scan. No LDS.
// ---------------------------------------------------------------------------
template <int NPL>
__device__ void fps_body(const float* __restrict__ ctr,
                         int Tt, int Ksel, int* __restrict__ rep,
                         int b, int lane)
{
  const float* base = ctr + (size_t)b * Tt * 3;
  float x[NPL], y[NPL], z[NPL], d[NPL];
  #pragma unroll
  for (int j = 0; j < NPL; ++j) {
    int idx = lane * NPL + j;
    x[j] = base[idx * 3 + 0];
    y[j] = base[idx * 3 + 1];
    z[j] = base[idx * 3 + 2];
    d[j] = INFINITY;
  }
  int cur = 0;
  // initial center = point 0 = lane 0's x[0] (static readlane)
  float cx = __uint_as_float((unsigned)__builtin_amdgcn_readlane(__float_as_int(x[0]), 0));
  float cy = __uint_as_float((unsigned)__builtin_amdgcn_readlane(__float_as_int(y[0]), 0));
  float cz = __uint_as_float((unsigned)__builtin_amdgcn_readlane(__float_as_int(z[0]), 0));
  for (int s = 0; s < Ksel; ++s) {
    if (lane == 0) rep[b * Ksel + s] = cur;
    float best = -INFINITY;
    int bidx = 0;
    float bx = 0.f, by = 0.f, bz = 0.f;
    #pragma unroll
    for (int j = 0; j < NPL; ++j) {
      float dx = __fsub_rn(x[j], cx);
      float dy = __fsub_rn(y[j], cy);
      float dz = __fsub_rn(z[j], cz);
      float dist = __fadd_rn(__fadd_rn(__fmul_rn(dx, dx), __fmul_rn(dy, dy)),
                             __fmul_rn(dz, dz));
      float nd = fminf(d[j], dist);
      d[j] = nd;
      bool gt = nd > best;
      best = gt ? nd : best;
      bidx = gt ? (lane * NPL + j) : bidx;
      bx = gt ? x[j] : bx;
      by = gt ? y[j] : by;
      bz = gt ? z[j] : bz;
    }
    // 16-lane row all-reduce max via DPP row_ror (VALU pipe)
    float rm = best;
    {
      int t;
      t = __builtin_amdgcn_mov_dpp(__float_as_int(rm), 0x121, 0xf, 0xf, false);
      rm = fmaxf(rm, __int_as_float(t));
      t = __builtin_amdgcn_mov_dpp(__float_as_int(rm), 0x122, 0xf, 0xf, false);
      rm = fmaxf(rm, __int_as_float(t));
      t = __builtin_amdgcn_mov_dpp(__float_as_int(rm), 0x124, 0xf, 0xf, false);
      rm = fmaxf(rm, __int_as_float(t));
      t = __builtin_amdgcn_mov_dpp(__float_as_int(rm), 0x128, 0xf, 0xf, false);
      rm = fmaxf(rm, __int_as_float(t));
    }
    float r0 = __uint_as_float((unsigned)__builtin_amdgcn_readlane(__float_as_int(rm), 0));
    float r1 = __uint_as_float((unsigned)__builtin_amdgcn_readlane(__float_as_int(rm), 16));
    float r2 = __uint_as_float((unsigned)__builtin_amdgcn_readlane(__float_as_int(rm), 32));
    float r3 = __uint_as_float((unsigned)__builtin_amdgcn_readlane(__float_as_int(rm), 48));
    float gm = fmaxf(fmaxf(r0, r1), fmaxf(r2, r3));
    // lowest lane with best==gm holds the first-index winner (exact ties)
    unsigned long long mask = __ballot(best == gm);
    int wl = __ffsll(mask) - 1;     // SGPR lane selector
    cur = __builtin_amdgcn_readlane(bidx, wl);
    cx = __uint_as_float((unsigned)__builtin_amdgcn_readlane(__float_as_int(bx), wl));
    cy = __uint_as_float((unsigned)__builtin_amdgcn_readlane(__float_as_int(by), wl));
    cz = __uint_as_float((unsigned)__builtin_amdgcn_readlane(__float_as_int(bz), wl));
  }
}

// ---------------------------------------------------------------------------
// kNN (index-exact, verified)
// ---------------------------------------------------------------------------
__global__ __launch_bounds__(256) void knn_kernel(
    const float* __restrict__ cq, const float* __restrict__ ct,
    int Tq, int Tt, int Kn, int* __restrict__ nn)
{
  int r = blockIdx.x;     // b*Tq + q
  int b = r / Tq;
  __shared__ float d2[1024];
  __shared__ float wv[4];
  __shared__ int wi[4];
  int tid = threadIdx.x, lane = tid & 63, wid = tid >> 6;
  float qx = cq[(size_t)r * 3 + 0];
  float qy = cq[(size_t)r * 3 + 1];
  float qz = cq[(size_t)r * 3 + 2];
  float sq = __fadd_rn(__fadd_rn(__fmul_rn(qx, qx), __fmul_rn(qy, qy)),
                       __fmul_rn(qz, qz));
  for (int t = tid; t < Tt; t += 256) {
    const float* tp = ct + ((size_t)b * Tt + t) * 3;
    float tx = tp[0], ty = tp[1], tz = tp[2];
    float st = __fadd_rn(__fadd_rn(__fmul_rn(tx, tx), __fmul_rn(ty, ty)),
                         __fmul_rn(tz, tz));
    float dot = __fadd_rn(__fadd_rn(__fmul_rn(qx, tx), __fmul_rn(qy, ty)),
                          __fmul_rn(qz, tz));
    d2[t] = __fsub_rn(__fadd_rn(sq, st), __fmul_rn(2.0f, dot));
  }
  __syncthreads();
  for (int j = 0; j < Kn; ++j) {
    float v = INFINITY; int ix = 0x7fffffff;
    for (int t = tid; t < Tt; t += 256) {
      float dv = d2[t];
      if (dv < v) { v = dv; ix = t; }
    }
    #pragma unroll
    for (int off = 32; off > 0; off >>= 1) {
      float ov = __shfl_down(v, off);
      int oi = __shfl_down(ix, off);
      if (ov < v || (ov == v && oi < ix)) { v = ov; ix = oi; }
    }
    if (lane == 0) { wv[wid] = v; wi[wid] = ix; }
    __syncthreads();
    if (tid == 0) {
      float bv = wv[0]; int bi = wi[0];
      for (int w = 1; w < 4; ++w)
        if (wv[w] < bv || (wv[w] == bv && wi[w] < bi)) { bv = wv[w]; bi = wi[w]; }
      nn[(size_t)r * Kn + j] = bi;
      d2[bi] = INFINITY;
    }
    __syncthreads();
  }
}

// ---------------------------------------------------------------------------
// Row gather
// ---------------------------------------------------------------------------
__global__ void gather_rows_kernel(
    const float* __restrict__ src, const int* __restrict__ idx,
    float* __restrict__ dst, int Tq, int Tt, int D, int total)
{
  int i = blockIdx.x * blockDim.x + threadIdx.x;
  if (i >= total) return;
  int d = i % D;
  int q = (i / D) % Tq;
  int b = i / (D * Tq);
  int s = idx[b * Tq + q];
  dst[i] = src[((size_t)b * Tt + s) * D + d];
}

// ---------------------------------------------------------------------------
// BatchNorm stats (apply is fused into GEMM A-staging)
// ---------------------------------------------------------------------------
__global__ __launch_bounds__(256) void bn_stats_kernel(
    const float* __restrict__ x1, int R1, const float* __restrict__ x2, int R2,
    float* __restrict__ part, int nch)
{
  int c = threadIdx.x;
  int chunk = blockIdx.x;
  int R = R1 + R2;
  int per = (R + nch - 1) / nch;
  int r0 = chunk * per;
  int r1 = min(r0 + per, R);
  float s = 0.f, ss = 0.f;
  for (int r = r0; r < r1; ++r) {
    float v = (r < R1) ? x1[(size_t)r * 256 + c] : x2[(size_t)(r - R1) * 256 + c];
    s += v;
    ss = fmaf(v, v, ss);
  }
  part[(size_t)chunk * 512 + c] = s;
  part[(size_t)chunk * 512 + 256 + c] = ss;
}

__global__ __launch_bounds__(256) void bn_finalize_kernel(
    const float* __restrict__ part, int nch, int R,
    float* __restrict__ mean, float* __restrict__ rstd)
{
  int c = threadIdx.x;
  float s = 0.f, ss = 0.f;
  for (int k = 0; k < nch; ++k) {
    s += part[(size_t)k * 512 + c];
    ss += part[(size_t)k * 512 + 256 + c];
  }
  float m = s / (float)R;
  float v = ss / (float)R - m * m;
  if (v < 0.f) v = 0.f;
  mean[c] = m;
  rstd[c] = rsqrtf(v + 1e-5f);
}

// ---------------------------------------------------------------------------
// fp32 tiled GEMM (kept for small prep/emb GEMMs)
// ---------------------------------------------------------------------------
__global__ __launch_bounds__(256) void gemm_kernel(
    const float* __restrict__ A, int lda,
    const float* __restrict__ W, int ldw,
    const float* __restrict__ bias, const float* __restrict__ resid,
    float* __restrict__ out, int M, int N, int K, int relu)
{
  __shared__ float As[32][68];
  __shared__ float Bs[32][68];
  int bm = blockIdx.y * 64;
  int bn = blockIdx.x * 64;
  int tid = threadIdx.x;
  int tx = tid & 15, ty = tid >> 4;
  int arow = tid >> 3;          // 0..31
  int ak = (tid & 7) * 4;       // 0,4,...,28
  int wk = tid >> 4;            // 0..15
  int wn = (tid & 15) * 4;      // 0..60
  float acc[4][4] = {{0.f}};
  for (int k0 = 0; k0 < K; k0 += 32) {
    #pragma unroll
    for (int h = 0; h < 2; ++h) {
      int row = bm + arow + h * 32;
      float4 a = (row < M)
          ? *(const float4*)&A[(size_t)row * lda + k0 + ak]
          : make_float4(0.f, 0.f, 0.f, 0.f);
      As[ak + 0][arow + h * 32] = a.x;
      As[ak + 1][arow + h * 32] = a.y;
      As[ak + 2][arow + h * 32] = a.z;
      As[ak + 3][arow + h * 32] = a.w;
    }
    #pragma unroll
    for (int h = 0; h < 2; ++h) {
      int krow = k0 + wk + h * 16;
      *(float4*)&Bs[wk + h * 16][wn] =
          *(const float4*)&W[(size_t)krow * ldw + bn + wn];
    }
    __syncthreads();
    #pragma unroll
    for (int k = 0; k < 32; ++k) {
      float4 a = *(const float4*)&As[k][ty * 4];
      float4 b = *(const float4*)&Bs[k][tx * 4];
      float av[4] = {a.x, a.y, a.z, a.w};
      float bv[4] = {b.x, b.y, b.z, b.w};
      #pragma unroll
      for (int i = 0; i < 4; ++i)
        #pragma unroll
        for (int j = 0; j < 4; ++j)
          acc[i][j] = fmaf(av[i], bv[j], acc[i][j]);
    }
    __syncthreads();
  }
  #pragma unroll
  for (int i = 0; i < 4; ++i) {
    int m = bm + ty * 4 + i;
    if (m >= M) continue;
    #pragma unroll
    for (int j = 0; j < 4; ++j) {
      int n = bn + tx * 4 + j;
      float v = acc[i][j];
      if (bias) v += bias[n];
      if (relu) v = fmaxf(v, 0.f);
      if (resid) v += resid[(size_t)m * N + n];
      out[(size_t)m * N + n] = v;
    }
  }
}

// ---------------------------------------------------------------------------
// Generic weight split+transpose: src f32 [K][N] (row stride ldw) ->
// dst bf16 hi/lo [N][K].
// ---------------------------------------------------------------------------
__global__ void splitT_kernel(
    const float* __restrict__ src, int ldw, int K, int N,
    __bf16* __restrict__ hi, __bf16* __restrict__ lo, int total)
{
  int i = blockIdx.x * blockDim.x + threadIdx.x;
  if (i >= total) return;
  int n = i / K;
  int k = i - n * K;
  float v = src[(size_t)k * ldw + n];
  __bf16 h = (__bf16)v;
  hi[i] = h;
  lo[i] = (__bf16)(v - (float)h);
}

// ---------------------------------------------------------------------------
// w2 transpose + bf16 hi/lo split (attn): w2[3][c][c'] f32 -> [3][c'][c]
// ---------------------------------------------------------------------------
__global__ __launch_bounds__(256) void split_w2_kernel(
    const float* __restrict__ w2, __bf16* __restrict__ hi,
    __bf16* __restrict__ lo)
{
  int i = blockIdx.x * 256 + threadIdx.x;   // over 3*65536
  int s = i >> 16;
  int e = i & 65535;
  int cp = e >> 8;   // c' (row of transposed)
  int cc = e & 255;  // c
  float v = w2[((size_t)s << 16) + cc * 256 + cp];
  __bf16 h = (__bf16)v;
  hi[i] = h;
  lo[i] = (__bf16)(v - (float)h);
}

// ---------------------------------------------------------------------------
// MFMA GEMM + optional fused BN on A + optional co-scheduled FPS blocks.
//   gemm blocks: blockIdx.x <  nbx  (BM=128, BN=64, BK=32, 256 thr)
//   fps  blocks: blockIdx.x == nbx && blockIdx.y < BB (one wave each;
//                register-only, no barriers -> divergent block paths safe)
// Requires M%128==0, N%64==0, K%32==0, and gridDim.y >= BB when fps fused.
// ---------------------------------------------------------------------------
template <int NPL>
__global__ __launch_bounds__(256) void gemm_mfma_kernel(
    const float* __restrict__ A, int lda,
    const __bf16* __restrict__ WThi, const __bf16* __restrict__ WTlo,
    const float* __restrict__ bias, const float* __restrict__ resid,
    float* __restrict__ out, int M, int N, int K, int relu,
    const float* __restrict__ bnm, const float* __restrict__ bnr,
    const float* __restrict__ bng, const float* __restrict__ bnb,
    int nbx,
    const float* __restrict__ fps_ctr, int fps_Tt, int fps_Ksel,
    int* __restrict__ fps_rep)
{
  __shared__ __align__(16) float As[128 * 36];
  if ((int)blockIdx.x >= nbx) {
    // co-scheduled FPS path (register-only)
    if (fps_rep == nullptr || (int)blockIdx.y >= BB) return;
    if ((int)threadIdx.x >= 64) return;
    fps_body<NPL>(fps_ctr, fps_Tt, fps_Ksel, fps_rep,
                  blockIdx.y, threadIdx.x);
    return;
  }
  int bm = blockIdx.y * 128;
  int bn = blockIdx.x * 64;
  int tid = threadIdx.x;
  int w = tid >> 6, lane = tid & 63;
  int jl = lane & 15;   // fragment row/col index
  int kg = lane >> 4;   // k-chunk group (8 elems)

  f32x4 acc[2][4];
  #pragma unroll
  for (int mt = 0; mt < 2; ++mt)
    #pragma unroll
    for (int nt = 0; nt < 4; ++nt) acc[mt][nt] = (f32x4){0.f, 0.f, 0.f, 0.f};

  for (int k0 = 0; k0 < K; k0 += 32) {
    // stage A tile [128][32] -> LDS [128][36], optional fused BN
    #pragma unroll
    for (int f = 0; f < 4; ++f) {
      int fi = tid + f * 256;       // float4 index 0..1023
      int row = fi >> 3, c4 = fi & 7;
      float4 v = *(const float4*)&A[(size_t)(bm + row) * lda + k0 + c4 * 4];
      if (bnm) {
        int kk = k0 + c4 * 4;
        float4 m4 = *(const float4*)&bnm[kk];
        float4 r4 = *(const float4*)&bnr[kk];
        float4 g4 = *(const float4*)&bng[kk];
        float4 b4 = *(const float4*)&bnb[kk];
        v.x = (v.x - m4.x) * r4.x * g4.x + b4.x;
        v.y = (v.y - m4.y) * r4.y * g4.y + b4.y;
        v.z = (v.z - m4.z) * r4.z * g4.z + b4.z;
        v.w = (v.w - m4.w) * r4.w * g4.w + b4.w;
      }
      *(float4*)&As[row * 36 + c4 * 4] = v;
    }
    __syncthreads();
    // A fragments (2 m-tiles), hi/lo convert
    bf16x8 ahi[2], alo[2];
    #pragma unroll
    for (int mt = 0; mt < 2; ++mt) {
      int row = (w * 2 + mt) * 16 + jl;
      float4 a0 = *(const float4*)&As[row * 36 + kg * 8];
      float4 a1 = *(const float4*)&As[row * 36 + kg * 8 + 4];
      float hv[8] = {a0.x, a0.y, a0.z, a0.w, a1.x, a1.y, a1.z, a1.w};
      #pragma unroll
      for (int i = 0; i < 8; ++i) {
        __bf16 t0 = (__bf16)hv[i];
        ahi[mt][i] = t0;
        alo[mt][i] = (__bf16)(hv[i] - (float)t0);
      }
    }
    #pragma unroll
    for (int nt = 0; nt < 4; ++nt) {
      size_t boff = (size_t)(bn + nt * 16 + jl) * K + k0 + kg * 8;
      bf16x8 bhi = *(const bf16x8*)(WThi + boff);
      bf16x8 blo = *(const bf16x8*)(WTlo + boff);
      #pragma unroll
      for (int mt = 0; mt < 2; ++mt) {
        acc[mt][nt] = __builtin_amdgcn_mfma_f32_16x16x32_bf16(alo[mt], bhi, acc[mt][nt], 0, 0, 0);
        acc[mt][nt] = __builtin_amdgcn_mfma_f32_16x16x32_bf16(ahi[mt], blo, acc[mt][nt], 0, 0, 0);
        acc[mt][nt] = __builtin_amdgcn_mfma_f32_16x16x32_bf16(ahi[mt], bhi, acc[mt][nt], 0, 0, 0);
      }
    }
    __syncthreads();
  }
  // epilogue: C/D layout col=jl, row=kg*4+qi (verified)
  #pragma unroll
  for (int mt = 0; mt < 2; ++mt)
    #pragma unroll
    for (int nt = 0; nt < 4; ++nt)
      #pragma unroll
      for (int qi = 0; qi < 4; ++qi) {
        int m = bm + (w * 2 + mt) * 16 + kg * 4 + qi;
        int n = bn + nt * 16 + jl;
        float v = acc[mt][nt][qi];
        if (bias) v += bias[n];
        if (relu) v = fmaxf(v, 0.f);
        if (resid) v += resid[(size_t)m * N + n];
        out[(size_t)m * N + n] = v;
      }
}

// ---------------------------------------------------------------------------
// MFMA attention v4 (verified round 8): 128 j-rows per block.
// KV is the merged [Mt][512] buffer: K = cols 0..255, V = cols 256..511.
// ---------------------------------------------------------------------------
template <int KN>
__global__ __launch_bounds__(256, 1) void attn4_kernel(
    const float* __restrict__ Qw, const float* __restrict__ KV,
    const int* __restrict__ nn,
    const float* __restrict__ b1, const __bf16* __restrict__ w2Thi,
    const __bf16* __restrict__ w2Tlo, const float* __restrict__ b2,
    const float* __restrict__ skip, float* __restrict__ out, int Tq, int Tt)
{
  constexpr int G  = 128 / KN;   // query rows per block
  constexpr int LD = 260;        // 2-way bank alias on C-store = free (m136)
  __shared__ float sim[128 * LD];  // 133 KB (<=160 KB/CU)
  __shared__ int nns[128];
  int r0 = blockIdx.x * G;       // flat query row base
  int b = r0 / Tq;
  int tid = threadIdx.x;
  if (tid < 128) nns[tid] = nn[(size_t)r0 * KN + tid];
  __syncthreads();

  int w = tid >> 6, lane = tid & 63;
  int jl = lane & 15;
  int kg = lane >> 4;
  int nt0 = w * 4;
  const float* kvb = KV + (size_t)b * Tt * 512;

  f32x4 acc[8][4];
  #pragma unroll
  for (int m = 0; m < 8; ++m)
    #pragma unroll
    for (int n = 0; n < 4; ++n) acc[m][n] = (f32x4){0.f, 0.f, 0.f, 0.f};

  const float* qp[8];
  const float* kp[8];
  #pragma unroll
  for (int mt = 0; mt < 8; ++mt) {
    int jr = mt * 16 + jl;
    qp[mt] = Qw + (size_t)(r0 + jr / KN) * 256;
    kp[mt] = kvb + (size_t)nns[jr] * 512;
  }

  #pragma unroll
  for (int ks = 0; ks < 8; ++ks) {
    int c0 = ks * 32 + kg * 8;
    float4 b1a = *(const float4*)(b1 + c0);
    float4 b1b = *(const float4*)(b1 + c0 + 4);
    bf16x8 ahi[8], alo[8];
    #pragma unroll
    for (int mt = 0; mt < 8; ++mt) {
      float4 qa = *(const float4*)(qp[mt] + c0);
      float4 qb = *(const float4*)(qp[mt] + c0 + 4);
      float4 ka = *(const float4*)(kp[mt] + c0);
      float4 kb = *(const float4*)(kp[mt] + c0 + 4);
      float h[8];
      h[0] = fmaxf(qa.x - ka.x + b1a.x, 0.f);
      h[1] = fmaxf(qa.y - ka.y + b1a.y, 0.f);
      h[2] = fmaxf(qa.z - ka.z + b1a.z, 0.f);
      h[3] = fmaxf(qa.w - ka.w + b1a.w, 0.f);
      h[4] = fmaxf(qb.x - kb.x + b1b.x, 0.f);
      h[5] = fmaxf(qb.y - kb.y + b1b.y, 0.f);
      h[6] = fmaxf(qb.z - kb.z + b1b.z, 0.f);
      h[7] = fmaxf(qb.w - kb.w + b1b.w, 0.f);
      #pragma unroll
      for (int i = 0; i < 8; ++i) {
        __bf16 t0 = (__bf16)h[i];
        ahi[mt][i] = t0;
        alo[mt][i] = (__bf16)(h[i] - (float)t0);
      }
    }
    #pragma unroll
    for (int t = 0; t < 4; ++t) {
      size_t boff = (size_t)((nt0 + t) * 16 + jl) * 256 + c0;
      bf16x8 bhi = *(const bf16x8*)(w2Thi + boff);
      bf16x8 blo = *(const bf16x8*)(w2Tlo + boff);
      #pragma unroll
      for (int mt = 0; mt < 8; ++mt) {
        acc[mt][t] = __builtin_amdgcn_mfma_f32_16x16x32_bf16(alo[mt], bhi, acc[mt][t], 0, 0, 0);
        acc[mt][t] = __builtin_amdgcn_mfma_f32_16x16x32_bf16(ahi[mt], blo, acc[mt][t], 0, 0, 0);
        acc[mt][t] = __builtin_amdgcn_mfma_f32_16x16x32_bf16(ahi[mt], bhi, acc[mt][t], 0, 0, 0);
      }
    }
  }
  #pragma unroll
  for (int mt = 0; mt < 8; ++mt)
    #pragma unroll
    for (int t = 0; t < 4; ++t)
      #pragma unroll
      for (int qi = 0; qi < 4; ++qi)
        sim[(mt * 16 + kg * 4 + qi) * LD + (nt0 + t) * 16 + jl] = acc[mt][t][qi];
  __syncthreads();

  int c = tid;
  float bb2 = b2[c];
  const float* vbb = kvb + 256;   // V columns of merged KV
  #pragma unroll
  for (int g = 0; g < G; ++g) {
    int jb = g * KN;
    float m = -INFINITY;
    #pragma unroll 8
    for (int jj = 0; jj < KN; ++jj)
      m = fmaxf(m, sim[(jb + jj) * LD + c] + bb2);
    float ssum = 0.f, o = 0.f;
    #pragma unroll 8
    for (int jj = 0; jj < KN; ++jj) {
      float e = expf(sim[(jb + jj) * LD + c] + bb2 - m);
      ssum += e;
      o = fmaf(e, vbb[(size_t)nns[jb + jj] * 512 + c], o);
    }
    int r = r0 + g;
    out[(size_t)r * 256 + c] = o / ssum + skip[(size_t)r * 256 + c];
  }
}

// ---------------------------------------------------------------------------
// Final head
// ---------------------------------------------------------------------------
__global__ void gmean_kernel(const float* __restrict__ tok,
                             float* __restrict__ out, int Tt)
{
  int i = blockIdx.x * blockDim.x + threadIdx.x;
  if (i >= BB * CC) return;
  int b = i >> 8;
  int c = i & 255;
  float s = 0.f;
  for (int t = 0; t < Tt; ++t) s += tok[((size_t)b * Tt + t) * 256 + c];
  out[i] = s / (float)Tt;
}

__global__ void embbn_kernel(const float* __restrict__ x,
                             const float* __restrict__ g,
                             const float* __restrict__ bta,
                             float* __restrict__ y)
{
  int e = blockIdx.x * blockDim.x + threadIdx.x;
  if (e >= EE) return;
  float s = 0.f;
  for (int r = 0; r < BB; ++r) s += x[r * EE + e];
  float m = s / (float)BB;
  float vs = 0.f;
  for (int r = 0; r < BB; ++r) {
    float d = x[r * EE + e] - m;
    vs = fmaf(d, d, vs);
  }
  float rs = rsqrtf(vs / (float)BB + 1e-5f);
  for (int r = 0; r < BB; ++r) {
    float val = (x[r * EE + e] - m) * rs * g[e] + bta[e];
    y[r * EE + e] = fmaxf(val, 0.f);
  }
}

__global__ __launch_bounds__(256) void topk_norm_kernel(
    const float* __restrict__ gin, float* __restrict__ out)
{
  int b = blockIdx.x, tid = threadIdx.x, lane = tid & 63, wid = tid >> 6;
  __shared__ float vals[512];
  __shared__ float wv[4];
  __shared__ int wi[4];
  __shared__ float sh;
  float g0 = gin[b * 512 + tid];
  float g1 = gin[b * 512 + 256 + tid];
  vals[tid] = g0;
  vals[256 + tid] = g1;
  __syncthreads();
  for (int it = 0; it < 64; ++it) {
    float v = vals[tid];
    int ix = tid;
    float u = vals[256 + tid];
    if (u > v) { v = u; ix = 256 + tid; }
    #pragma unroll
    for (int off = 32; off > 0; off >>= 1) {
      float ov = __shfl_down(v, off);
      int oi = __shfl_down(ix, off);
      if (ov > v || (ov == v && oi < ix)) { v = ov; ix = oi; }
    }
    if (lane == 0) { wv[wid] = v; wi[wid] = ix; }
    __syncthreads();
    if (tid == 0) {
      float bv = wv[0]; int bi = wi[0];
      for (int w = 1; w < 4; ++w)
        if (wv[w] > bv || (wv[w] == bv && wi[w] < bi)) { bv = wv[w]; bi = wi[w]; }
      vals[bi] = -INFINITY;
      sh = bv;
    }
    __syncthreads();
  }
  float thr = sh;
  float m0 = (g0 >= thr) ? g0 : 0.f;
  float m1 = (g1 >= thr) ? g1 : 0.f;
  float ss = m0 * m0 + m1 * m1;
  #pragma unroll
  for (int off = 32; off > 0; off >>= 1) ss += __shfl_down(ss, off);
  if (lane == 0) wv[wid] = ss;
  __syncthreads();
  if (tid == 0) {
    float t = wv[0] + wv[1] + wv[2] + wv[3];
    sh = fmaxf(sqrtf(t), 1e-12f);
  }
  __syncthreads();
  float n = sh;
  out[b * 512 + tid] = m0 / n;
  out[b * 512 + 256 + tid] = m1 / n;
}

// ---------------------------------------------------------------------------
// Host orchestration
// ---------------------------------------------------------------------------
extern "C" void kernel_launch(void* const* d_in, const int* in_sizes, int n_in,
                              void* d_out, int out_size, void* d_ws, size_t ws_size,
                              hipStream_t stream)
{
  const float* tokens  = (const float*)d_in[0];
  const float* centers = (const float*)d_in[1];
  // d_in[2] = lrfs: dead in the reference
  const float* wq      = (const float*)d_in[3];
  const float* wkv     = (const float*)d_in[4];
  const float* mlp_w1  = (const float*)d_in[5];
  const float* mlp_b1  = (const float*)d_in[6];
  const float* mlp_w2  = (const float*)d_in[7];
  const float* mlp_b2  = (const float*)d_in[8];
  const float* bn1_g   = (const float*)d_in[9];
  const float* bn1_b   = (const float*)d_in[10];
  const float* bn2_g   = (const float*)d_in[11];
  const float* bn2_b   = (const float*)d_in[12];
  const float* att_w1  = (const float*)d_in[13];
  const float* att_b1  = (const float*)d_in[14];
  const float* att_w2  = (const float*)d_in[15];
  const float* att_b2  = (const float*)d_in[16];
  const float* emb_w   = (const float*)d_in[17];
  const float* emb_b   = (const float*)d_in[18];
  const float* embn_g  = (const float*)d_in[19];
  const float* embn_b  = (const float*)d_in[20];
  (void)in_sizes; (void)n_in; (void)out_size; (void)ws_size;

  char* ws = (char*)d_ws;
  size_t off = 0;
  auto alloc = [&](size_t bytes) -> void* {
    void* p = ws + off;
    off += (bytes + 255) & ~(size_t)255;
    return p;
  };
  const size_t tokMax  = (size_t)BB * 512 * CC * 4;   // 8 MB
  float* tokA     = (float*)alloc(tokMax);
  float* tokB     = (float*)alloc(tokMax);
  float* ctrA     = (float*)alloc((size_t)BB * 512 * 3 * 4);
  float* ctrB     = (float*)alloc((size_t)BB * 256 * 3 * 4);
  float* ctrC     = (float*)alloc((size_t)BB * 128 * 3 * 4);
  float* tokq_raw = (float*)alloc(tokMax);
  float* Qw1      = (float*)alloc(tokMax);
  float* KVbuf    = (float*)alloc((size_t)BB * 1024 * 512 * 4);  // 32 MB
  float* tq1      = (float*)alloc(tokMax);
  float* mlph     = (float*)alloc((size_t)BB * 512 * 512 * 4);
  float* WFq      = (float*)alloc((size_t)3 * CC * CC * 4);
  float* WFk      = (float*)alloc((size_t)3 * CC * CC * 4);
  __bf16* w2Thi   = (__bf16*)alloc((size_t)3 * CC * CC * 2);
  __bf16* w2Tlo   = (__bf16*)alloc((size_t)3 * CC * CC * 2);
  __bf16* wfqThi  = (__bf16*)alloc((size_t)3 * CC * CC * 2);
  __bf16* wfqTlo  = (__bf16*)alloc((size_t)3 * CC * CC * 2);
  __bf16* wkvThi  = (__bf16*)alloc((size_t)3 * 512 * CC * 2);  // [K|V] rows
  __bf16* wkvTlo  = (__bf16*)alloc((size_t)3 * 512 * CC * 2);
  __bf16* w1Thi   = (__bf16*)alloc((size_t)3 * CC * 512 * 2);
  __bf16* w1Tlo   = (__bf16*)alloc((size_t)3 * CC * 512 * 2);
  __bf16* wm2Thi  = (__bf16*)alloc((size_t)3 * 512 * CC * 2);
  __bf16* wm2Tlo  = (__bf16*)alloc((size_t)3 * 512 * CC * 2);
  int*   rep0     = (int*)alloc((size_t)BB * 512 * 4);
  int*   rep1     = (int*)alloc((size_t)BB * 256 * 4);
  int*   rep2     = (int*)alloc((size_t)BB * 128 * 4);
  int*   nnb      = (int*)alloc((size_t)BB * 512 * 64 * 4);
  float* bnpart   = (float*)alloc((size_t)64 * 512 * 4);
  float* bn1mean  = (float*)alloc(256 * 4);
  float* bn1rstd  = (float*)alloc(256 * 4);
  float* bn2mean  = (float*)alloc(256 * 4);
  float* bn2rstd  = (float*)alloc(256 * 4);
  float* gmeanb   = (float*)alloc((size_t)BB * CC * 4);
  float* gembb    = (float*)alloc((size_t)BB * EE * 4);
  float* grelub   = (float*)alloc((size_t)BB * EE * 4);

  const int NC[3] = {512, 256, 128};
  const int NN[3] = {16, 32, 64};
  int* reps[3] = {rep0, rep1, rep2};
  float* ctrq[3] = {ctrA, ctrB, ctrC};

  // One-time weight prep.
  for (int i = 0; i < 3; ++i) {
    gemm_kernel<<<dim3(4, 4), 256, 0, stream>>>(
        wq + (size_t)i * CC * CC, CC, att_w1 + (size_t)i * CC * CC, CC,
        nullptr, nullptr, WFq + (size_t)i * CC * CC, CC, CC, CC, 0);
    gemm_kernel<<<dim3(4, 4), 256, 0, stream>>>(
        wkv + (size_t)i * CC * 512, 512, att_w1 + (size_t)i * CC * CC, CC,
        nullptr, nullptr, WFk + (size_t)i * CC * CC, CC, CC, CC, 0);
  }
  split_w2_kernel<<<3 * 65536 / 256, 256, 0, stream>>>(att_w2, w2Thi, w2Tlo);
  for (int i = 0; i < 3; ++i) {
    int t1 = CC * CC;
    splitT_kernel<<<(t1 + 255) / 256, 256, 0, stream>>>(
        WFq + (size_t)i * CC * CC, CC, CC, CC,
        wfqThi + (size_t)i * t1, wfqTlo + (size_t)i * t1, t1);
    // merged KV weights [512][256]: rows 0..255 = folded-K, 256..511 = V
    splitT_kernel<<<(t1 + 255) / 256, 256, 0, stream>>>(
        WFk + (size_t)i * CC * CC, CC, CC, CC,
        wkvThi + (size_t)i * 512 * CC, wkvTlo + (size_t)i * 512 * CC, t1);
    splitT_kernel<<<(t1 + 255) / 256, 256, 0, stream>>>(
        wkv + (size_t)i * CC * 512 + CC, 512, CC, CC,
        wkvThi + (size_t)i * 512 * CC + t1, wkvTlo + (size_t)i * 512 * CC + t1, t1);
    int t2 = CC * 512;   // mlp_w1: K=256, N=512
    splitT_kernel<<<(t2 + 255) / 256, 256, 0, stream>>>(
        mlp_w1 + (size_t)i * t2, 512, CC, 512,
        w1Thi + (size_t)i * t2, w1Tlo + (size_t)i * t2, t2);
    // mlp_w2: K=512, N=256
    splitT_kernel<<<(t2 + 255) / 256, 256, 0, stream>>>(
        mlp_w2 + (size_t)i * t2, CC, 512, CC,
        wm2Thi + (size_t)i * t2, wm2Tlo + (size_t)i * t2, t2);
  }

  const float* cur_tok = tokens;
  const float* cur_ctr = centers;
  int curTt = TT0;
  float* tok_bufs[2] = {tokA, tokB};

  // fps0 (on raw centers) is co-scheduled with the stage-0 KV projection.
  for (int i = 0; i < 3; ++i) {
    int Tq = NC[i], Kn = NN[i], Tt = curTt;
    float* ctr_q = ctrq[i];
    float* tok_next = tok_bufs[i & 1];
    int M = BB * Tq;
    int Mt = BB * Tt;
    int* rep = reps[i];

    const float *b1m = nullptr, *b1r = nullptr, *b1g = nullptr, *b1b = nullptr;

    if (i == 0) {
      // KV0 projection (A=tokens, no BN) + co-scheduled fps0
      gemm_mfma_kernel<16><<<dim3(512 / 64 + 1, Mt / 128), 256, 0, stream>>>(
          tokens, CC, wkvThi, wkvTlo, nullptr, nullptr, KVbuf,
          Mt, 512, CC, 0, nullptr, nullptr, nullptr, nullptr,
          512 / 64, centers, 1024, 512, rep0);
    }

    // gathers (need rep_i) + kNN
    {
      int tot = BB * Tq * 3;
      gather_rows_kernel<<<(tot + 255) / 256, 256, 0, stream>>>(
          cur_ctr, rep, ctr_q, Tq, Tt, 3, tot);
    }
    {
      int tot = M * CC;
      gather_rows_kernel<<<(tot + 255) / 256, 256, 0, stream>>>(
          cur_tok, rep, tokq_raw, Tq, Tt, CC, tot);
    }
    knn_kernel<<<M, 256, 0, stream>>>(ctr_q, cur_ctr, Tq, Tt, Kn, nnb);

    if (i > 0) {
      // BN1 stats over concat(query, target); apply fused into GEMMs
      bn_stats_kernel<<<64, 256, 0, stream>>>(tokq_raw, M, cur_tok, Mt, bnpart, 64);
      bn_finalize_kernel<<<1, 256, 0, stream>>>(bnpart, 64, M + Mt, bn1mean, bn1rstd);
      b1m = bn1mean; b1r = bn1rstd; b1g = bn1_g + i * CC; b1b = bn1_b + i * CC;
      // KV projection with fused BN1; stage 1 also co-schedules fps2 (ctrB
      // is ready from this stage's center gather).
      if (i == 1)
        gemm_mfma_kernel<4><<<dim3(512 / 64 + 1, Mt / 128), 256, 0, stream>>>(
            cur_tok, CC, wkvThi + (size_t)i * 512 * CC, wkvTlo + (size_t)i * 512 * CC,
            nullptr, nullptr, KVbuf, Mt, 512, CC, 0, b1m, b1r, b1g, b1b,
            512 / 64, ctrB, 256, 128, rep2);
      else
        gemm_mfma_kernel<4><<<dim3(512 / 64, Mt / 128), 256, 0, stream>>>(
            cur_tok, CC, wkvThi + (size_t)i * 512 * CC, wkvTlo + (size_t)i * 512 * CC,
            nullptr, nullptr, KVbuf, Mt, 512, CC, 0, b1m, b1r, b1g, b1b,
            512 / 64, nullptr, 0, 0, nullptr);
    }

    // Q projection (folded weights, fused BN1)
    gemm_mfma_kernel<4><<<dim3(CC / 64, M / 128), 256, 0, stream>>>(
        tokq_raw, CC, wfqThi + (size_t)i * CC * CC, wfqTlo + (size_t)i * CC * CC,
        nullptr, nullptr, Qw1, M, CC, CC, 0, b1m, b1r, b1g, b1b,
        CC / 64, nullptr, 0, 0, nullptr);

    // Fused neighborhood attention via MFMA, 128 rows/block (+ skip)
    if (Kn == 16)
      attn4_kernel<16><<<dim3(M / 8), 256, 0, stream>>>(
          Qw1, KVbuf, nnb, att_b1 + i * CC,
          w2Thi + (size_t)i * CC * CC, w2Tlo + (size_t)i * CC * CC,
          att_b2 + i * CC, tokq_raw, tq1, Tq, Tt);
    else if (Kn == 32)
      attn4_kernel<32><<<dim3(M / 4), 256, 0, stream>>>(
          Qw1, KVbuf, nnb, att_b1 + i * CC,
          w2Thi + (size_t)i * CC * CC, w2Tlo + (size_t)i * CC * CC,
          att_b2 + i * CC, tokq_raw, tq1, Tq, Tt);
    else
      attn4_kernel<64><<<dim3(M / 2), 256, 0, stream>>>(
          Qw1, KVbuf, nnb, att_b1 + i * CC,
          w2Thi + (size_t)i * CC * CC, w2Tlo + (size_t)i * CC * CC,
          att_b2 + i * CC, tokq_raw, tq1, Tq, Tt);

    // BN2 stats + MLP (+ skip2); BN2 fused into MLP1. Stage 0's MLP1 also
    // co-schedules fps1 (ctrA ready from this stage's center gather).
    bn_stats_kernel<<<64, 256, 0, stream>>>(tq1, M, tq1, 0, bnpart, 64);
    bn_finalize_kernel<<<1, 256, 0, stream>>>(bnpart, 64, M, bn2mean, bn2rstd);
    if (i == 0)
      gemm_mfma_kernel<8><<<dim3(512 / 64 + 1, M / 128), 256, 0, stream>>>(
          tq1, CC, w1Thi + (size_t)i * CC * 512, w1Tlo + (size_t)i * CC * 512,
          mlp_b1 + i * 512, nullptr, mlph, M, 512, CC, 1,
          bn2mean, bn2rstd, bn2_g + i * CC, bn2_b + i * CC,
          512 / 64, ctrA, 512, 256, rep1);
    else
      gemm_mfma_kernel<4><<<dim3(512 / 64, M / 128), 256, 0, stream>>>(
          tq1, CC, w1Thi + (size_t)i * CC * 512, w1Tlo + (size_t)i * CC * 512,
          mlp_b1 + i * 512, nullptr, mlph, M, 512, CC, 1,
          bn2mean, bn2rstd, bn2_g + i * CC, bn2_b + i * CC,
          512 / 64, nullptr, 0, 0, nullptr);
    gemm_mfma_kernel<4><<<dim3(CC / 64, M / 128), 256, 0, stream>>>(
        mlph, 512, wm2Thi + (size_t)i * 512 * CC, wm2Tlo + (size_t)i * 512 * CC,
        mlp_b2 + i * CC, tq1, tok_next, M, CC, 512, 0,
        nullptr, nullptr, nullptr, nullptr,
        CC / 64, nullptr, 0, 0, nullptr);

    cur_tok = tok_next;
    cur_ctr = ctr_q;
    curTt = Tq;
  }

  // Final head
  gmean_kernel<<<(BB * CC + 255) / 256, 256, 0, stream>>>(cur_tok, gmeanb, curTt);
  gemm_kernel<<<dim3(EE / 64, 1), 256, 0, stream>>>(
      gmeanb, CC, emb_w, EE, emb_b, nullptr, gembb, BB, EE, CC, 0);
  embbn_kernel<<<2, 256, 0, stream>>>(gembb, embn_g, embn_b, grelub);
  topk_norm_kernel<<<BB, 256, 0, stream>>>(grelub, (float*)d_out);
}

// Round 15
// 1833.756 us; speedup vs baseline: 1.0794x; 1.0794x over previous
//
#include <hip/hip_runtime.h>
#include <cstdint>
#include <cmath>

// Problem constants
static constexpr int BB = 16;    // batch
static constexpr int TT0 = 1024; // initial tokens
static constexpr int CC = 256;   // channels
static constexpr int EE = 512;   // embedding

typedef __bf16 bf16x8 __attribute__((ext_vector_type(8)));
typedef float  f32x4  __attribute__((ext_vector_type(4)));

// ---------------------------------------------------------------------------
// FPS body v5 (verified round 12/13; v6 regression reverted): one 64-lane
// wave per batch. u64 key tracking + DPP row_ror reduce + ballot/ffs/readlane
// index recovery; center broadcast via uniform-address LDS read.
// Distance math bit-identical to reference scan. sp = 16KB LDS scratch.
// ---------------------------------------------------------------------------
template <int NPL>
__device__ void fps_body(float4* sp, const float* __restrict__ ctr,
                         int Tt, int Ksel, int* __restrict__ rep,
                         int b, int lane)
{
  const float* base = ctr + (size_t)b * Tt * 3;
  float x[NPL], y[NPL], z[NPL], d[NPL];
  #pragma unroll
  for (int j = 0; j < NPL; ++j) {
    int idx = lane * NPL + j;
    x[j] = base[idx * 3 + 0];
    y[j] = base[idx * 3 + 1];
    z[j] = base[idx * 3 + 2];
    d[j] = INFINITY;
    sp[idx] = make_float4(x[j], y[j], z[j], 0.f);
  }
  int cur = 0;
  for (int s = 0; s < Ksel; ++s) {
    if (lane == 0) rep[b * Ksel + s] = cur;
    float4 cpt = sp[cur];  // uniform address -> broadcast
    unsigned long long key = 0ull;
    #pragma unroll
    for (int j = 0; j < NPL; ++j) {
      float dx = __fsub_rn(x[j], cpt.x);
      float dy = __fsub_rn(y[j], cpt.y);
      float dz = __fsub_rn(z[j], cpt.z);
      float dist = __fadd_rn(__fadd_rn(__fmul_rn(dx, dx), __fmul_rn(dy, dy)),
                             __fmul_rn(dz, dz));
      float nd = fminf(d[j], dist);
      d[j] = nd;
      unsigned long long kj =
          ((unsigned long long)__float_as_uint(nd) << 32) |
          (unsigned)(0xFFFFFFFFu - (unsigned)(lane * NPL + j));
      key = (kj > key) ? kj : key;
    }
    // d >= 0 finite: float order == bit order; no NaN/-0 possible.
    float ld = __uint_as_float((unsigned)(key >> 32));
    float rm = ld;
    {
      int t;
      t = __builtin_amdgcn_mov_dpp(__float_as_int(rm), 0x121, 0xf, 0xf, false);
      rm = fmaxf(rm, __int_as_float(t));
      t = __builtin_amdgcn_mov_dpp(__float_as_int(rm), 0x122, 0xf, 0xf, false);
      rm = fmaxf(rm, __int_as_float(t));
      t = __builtin_amdgcn_mov_dpp(__float_as_int(rm), 0x124, 0xf, 0xf, false);
      rm = fmaxf(rm, __int_as_float(t));
      t = __builtin_amdgcn_mov_dpp(__float_as_int(rm), 0x128, 0xf, 0xf, false);
      rm = fmaxf(rm, __int_as_float(t));
    }
    float r0 = __uint_as_float((unsigned)__builtin_amdgcn_readlane(__float_as_int(rm), 0));
    float r1 = __uint_as_float((unsigned)__builtin_amdgcn_readlane(__float_as_int(rm), 16));
    float r2 = __uint_as_float((unsigned)__builtin_amdgcn_readlane(__float_as_int(rm), 32));
    float r3 = __uint_as_float((unsigned)__builtin_amdgcn_readlane(__float_as_int(rm), 48));
    float gm = fmaxf(fmaxf(r0, r1), fmaxf(r2, r3));
    unsigned long long mask = __ballot(ld == gm);
    int wl = __ffsll(mask) - 1;
    unsigned lowkey = (unsigned)__builtin_amdgcn_readlane((int)(unsigned)key, wl);
    cur = (int)(0xFFFFFFFFu - lowkey);
  }
}

// ---------------------------------------------------------------------------
// kNN (index-exact, verified)
// ---------------------------------------------------------------------------
__global__ __launch_bounds__(256) void knn_kernel(
    const float* __restrict__ cq, const float* __restrict__ ct,
    int Tq, int Tt, int Kn, int* __restrict__ nn)
{
  int r = blockIdx.x;     // b*Tq + q
  int b = r / Tq;
  __shared__ float d2[1024];
  __shared__ float wv[4];
  __shared__ int wi[4];
  int tid = threadIdx.x, lane = tid & 63, wid = tid >> 6;
  float qx = cq[(size_t)r * 3 + 0];
  float qy = cq[(size_t)r * 3 + 1];
  float qz = cq[(size_t)r * 3 + 2];
  float sq = __fadd_rn(__fadd_rn(__fmul_rn(qx, qx), __fmul_rn(qy, qy)),
                       __fmul_rn(qz, qz));
  for (int t = tid; t < Tt; t += 256) {
    const float* tp = ct + ((size_t)b * Tt + t) * 3;
    float tx = tp[0], ty = tp[1], tz = tp[2];
    float st = __fadd_rn(__fadd_rn(__fmul_rn(tx, tx), __fmul_rn(ty, ty)),
                         __fmul_rn(tz, tz));
    float dot = __fadd_rn(__fadd_rn(__fmul_rn(qx, tx), __fmul_rn(qy, ty)),
                          __fmul_rn(qz, tz));
    d2[t] = __fsub_rn(__fadd_rn(sq, st), __fmul_rn(2.0f, dot));
  }
  __syncthreads();
  for (int j = 0; j < Kn; ++j) {
    float v = INFINITY; int ix = 0x7fffffff;
    for (int t = tid; t < Tt; t += 256) {
      float dv = d2[t];
      if (dv < v) { v = dv; ix = t; }
    }
    #pragma unroll
    for (int off = 32; off > 0; off >>= 1) {
      float ov = __shfl_down(v, off);
      int oi = __shfl_down(ix, off);
      if (ov < v || (ov == v && oi < ix)) { v = ov; ix = oi; }
    }
    if (lane == 0) { wv[wid] = v; wi[wid] = ix; }
    __syncthreads();
    if (tid == 0) {
      float bv = wv[0]; int bi = wi[0];
      for (int w = 1; w < 4; ++w)
        if (wv[w] < bv || (wv[w] == bv && wi[w] < bi)) { bv = wv[w]; bi = wi[w]; }
      nn[(size_t)r * Kn + j] = bi;
      d2[bi] = INFINITY;
    }
    __syncthreads();
  }
}

// ---------------------------------------------------------------------------
// Row gather
// ---------------------------------------------------------------------------
__global__ void gather_rows_kernel(
    const float* __restrict__ src, const int* __restrict__ idx,
    float* __restrict__ dst, int Tq, int Tt, int D, int total)
{
  int i = blockIdx.x * blockDim.x + threadIdx.x;
  if (i >= total) return;
  int d = i % D;
  int q = (i / D) % Tq;
  int b = i / (D * Tq);
  int s = idx[b * Tq + q];
  dst[i] = src[((size_t)b * Tt + s) * D + d];
}

// ---------------------------------------------------------------------------
// BatchNorm stats (apply is fused into GEMM A-staging)
// ---------------------------------------------------------------------------
__global__ __launch_bounds__(256) void bn_stats_kernel(
    const float* __restrict__ x1, int R1, const float* __restrict__ x2, int R2,
    float* __restrict__ part, int nch)
{
  int c = threadIdx.x;
  int chunk = blockIdx.x;
  int R = R1 + R2;
  int per = (R + nch - 1) / nch;
  int r0 = chunk * per;
  int r1 = min(r0 + per, R);
  float s = 0.f, ss = 0.f;
  for (int r = r0; r < r1; ++r) {
    float v = (r < R1) ? x1[(size_t)r * 256 + c] : x2[(size_t)(r - R1) * 256 + c];
    s += v;
    ss = fmaf(v, v, ss);
  }
  part[(size_t)chunk * 512 + c] = s;
  part[(size_t)chunk * 512 + 256 + c] = ss;
}

__global__ __launch_bounds__(256) void bn_finalize_kernel(
    const float* __restrict__ part, int nch, int R,
    float* __restrict__ mean, float* __restrict__ rstd)
{
  int c = threadIdx.x;
  float s = 0.f, ss = 0.f;
  for (int k = 0; k < nch; ++k) {
    s += part[(size_t)k * 512 + c];
    ss += part[(size_t)k * 512 + 256 + c];
  }
  float m = s / (float)R;
  float v = ss / (float)R - m * m;
  if (v < 0.f) v = 0.f;
  mean[c] = m;
  rstd[c] = rsqrtf(v + 1e-5f);
}

// ---------------------------------------------------------------------------
// fp32 tiled GEMM (kept for small prep/emb GEMMs)
// ---------------------------------------------------------------------------
__global__ __launch_bounds__(256) void gemm_kernel(
    const float* __restrict__ A, int lda,
    const float* __restrict__ W, int ldw,
    const float* __restrict__ bias, const float* __restrict__ resid,
    float* __restrict__ out, int M, int N, int K, int relu)
{
  __shared__ float As[32][68];
  __shared__ float Bs[32][68];
  int bm = blockIdx.y * 64;
  int bn = blockIdx.x * 64;
  int tid = threadIdx.x;
  int tx = tid & 15, ty = tid >> 4;
  int arow = tid >> 3;          // 0..31
  int ak = (tid & 7) * 4;       // 0,4,...,28
  int wk = tid >> 4;            // 0..15
  int wn = (tid & 15) * 4;      // 0..60
  float acc[4][4] = {{0.f}};
  for (int k0 = 0; k0 < K; k0 += 32) {
    #pragma unroll
    for (int h = 0; h < 2; ++h) {
      int row = bm + arow + h * 32;
      float4 a = (row < M)
          ? *(const float4*)&A[(size_t)row * lda + k0 + ak]
          : make_float4(0.f, 0.f, 0.f, 0.f);
      As[ak + 0][arow + h * 32] = a.x;
      As[ak + 1][arow + h * 32] = a.y;
      As[ak + 2][arow + h * 32] = a.z;
      As[ak + 3][arow + h * 32] = a.w;
    }
    #pragma unroll
    for (int h = 0; h < 2; ++h) {
      int krow = k0 + wk + h * 16;
      *(float4*)&Bs[wk + h * 16][wn] =
          *(const float4*)&W[(size_t)krow * ldw + bn + wn];
    }
    __syncthreads();
    #pragma unroll
    for (int k = 0; k < 32; ++k) {
      float4 a = *(const float4*)&As[k][ty * 4];
      float4 b = *(const float4*)&Bs[k][tx * 4];
      float av[4] = {a.x, a.y, a.z, a.w};
      float bv[4] = {b.x, b.y, b.z, b.w};
      #pragma unroll
      for (int i = 0; i < 4; ++i)
        #pragma unroll
        for (int j = 0; j < 4; ++j)
          acc[i][j] = fmaf(av[i], bv[j], acc[i][j]);
    }
    __syncthreads();
  }
  #pragma unroll
  for (int i = 0; i < 4; ++i) {
    int m = bm + ty * 4 + i;
    if (m >= M) continue;
    #pragma unroll
    for (int j = 0; j < 4; ++j) {
      int n = bn + tx * 4 + j;
      float v = acc[i][j];
      if (bias) v += bias[n];
      if (relu) v = fmaxf(v, 0.f);
      if (resid) v += resid[(size_t)m * N + n];
      out[(size_t)m * N + n] = v;
    }
  }
}

// ---------------------------------------------------------------------------
// Generic weight split+transpose: src f32 [K][N] (row stride ldw) ->
// dst bf16 hi/lo [N][K].
// ---------------------------------------------------------------------------
__global__ void splitT_kernel(
    const float* __restrict__ src, int ldw, int K, int N,
    __bf16* __restrict__ hi, __bf16* __restrict__ lo, int total)
{
  int i = blockIdx.x * blockDim.x + threadIdx.x;
  if (i >= total) return;
  int n = i / K;
  int k = i - n * K;
  float v = src[(size_t)k * ldw + n];
  __bf16 h = (__bf16)v;
  hi[i] = h;
  lo[i] = (__bf16)(v - (float)h);
}

// ---------------------------------------------------------------------------
// w2 transpose + bf16 hi/lo split (attn): w2[3][c][c'] f32 -> [3][c'][c]
// ---------------------------------------------------------------------------
__global__ __launch_bounds__(256) void split_w2_kernel(
    const float* __restrict__ w2, __bf16* __restrict__ hi,
    __bf16* __restrict__ lo)
{
  int i = blockIdx.x * 256 + threadIdx.x;   // over 3*65536
  int s = i >> 16;
  int e = i & 65535;
  int cp = e >> 8;   // c' (row of transposed)
  int cc = e & 255;  // c
  float v = w2[((size_t)s << 16) + cc * 256 + cp];
  __bf16 h = (__bf16)v;
  hi[i] = h;
  lo[i] = (__bf16)(v - (float)h);
}

// ---------------------------------------------------------------------------
// MFMA GEMM + optional fused BN on A + optional co-scheduled FPS blocks.
//   gemm blocks: blockIdx.x <  nbx  (BM=128, BN=64, BK=32, 256 thr)
//   fps  blocks: blockIdx.x == nbx && blockIdx.y < BB (one wave each; the
//                fps LDS scratch overlays the gemm As buffer; no barriers on
//                the fps path so divergent block paths are safe)
// Requires M%128==0, N%64==0, K%32==0, and gridDim.y >= BB when fps fused.
// ---------------------------------------------------------------------------
template <int NPL>
__global__ __launch_bounds__(256) void gemm_mfma_kernel(
    const float* __restrict__ A, int lda,
    const __bf16* __restrict__ WThi, const __bf16* __restrict__ WTlo,
    const float* __restrict__ bias, const float* __restrict__ resid,
    float* __restrict__ out, int M, int N, int K, int relu,
    const float* __restrict__ bnm, const float* __restrict__ bnr,
    const float* __restrict__ bng, const float* __restrict__ bnb,
    int nbx,
    const float* __restrict__ fps_ctr, int fps_Tt, int fps_Ksel,
    int* __restrict__ fps_rep)
{
  __shared__ __align__(16) float As[128 * 36];
  if ((int)blockIdx.x >= nbx) {
    // co-scheduled FPS path
    if (fps_rep == nullptr || (int)blockIdx.y >= BB) return;
    if ((int)threadIdx.x >= 64) return;
    fps_body<NPL>((float4*)As, fps_ctr, fps_Tt, fps_Ksel, fps_rep,
                  blockIdx.y, threadIdx.x);
    return;
  }
  int bm = blockIdx.y * 128;
  int bn = blockIdx.x * 64;
  int tid = threadIdx.x;
  int w = tid >> 6, lane = tid & 63;
  int jl = lane & 15;   // fragment row/col index
  int kg = lane >> 4;   // k-chunk group (8 elems)

  f32x4 acc[2][4];
  #pragma unroll
  for (int mt = 0; mt < 2; ++mt)
    #pragma unroll
    for (int nt = 0; nt < 4; ++nt) acc[mt][nt] = (f32x4){0.f, 0.f, 0.f, 0.f};

  for (int k0 = 0; k0 < K; k0 += 32) {
    // stage A tile [128][32] -> LDS [128][36], optional fused BN
    #pragma unroll
    for (int f = 0; f < 4; ++f) {
      int fi = tid + f * 256;       // float4 index 0..1023
      int row = fi >> 3, c4 = fi & 7;
      float4 v = *(const float4*)&A[(size_t)(bm + row) * lda + k0 + c4 * 4];
      if (bnm) {
        int kk = k0 + c4 * 4;
        float4 m4 = *(const float4*)&bnm[kk];
        float4 r4 = *(const float4*)&bnr[kk];
        float4 g4 = *(const float4*)&bng[kk];
        float4 b4 = *(const float4*)&bnb[kk];
        v.x = (v.x - m4.x) * r4.x * g4.x + b4.x;
        v.y = (v.y - m4.y) * r4.y * g4.y + b4.y;
        v.z = (v.z - m4.z) * r4.z * g4.z + b4.z;
        v.w = (v.w - m4.w) * r4.w * g4.w + b4.w;
      }
      *(float4*)&As[row * 36 + c4 * 4] = v;
    }
    __syncthreads();
    // A fragments (2 m-tiles), hi/lo convert
    bf16x8 ahi[2], alo[2];
    #pragma unroll
    for (int mt = 0; mt < 2; ++mt) {
      int row = (w * 2 + mt) * 16 + jl;
      float4 a0 = *(const float4*)&As[row * 36 + kg * 8];
      float4 a1 = *(const float4*)&As[row * 36 + kg * 8 + 4];
      float hv[8] = {a0.x, a0.y, a0.z, a0.w, a1.x, a1.y, a1.z, a1.w};
      #pragma unroll
      for (int i = 0; i < 8; ++i) {
        __bf16 t0 = (__bf16)hv[i];
        ahi[mt][i] = t0;
        alo[mt][i] = (__bf16)(hv[i] - (float)t0);
      }
    }
    #pragma unroll
    for (int nt = 0; nt < 4; ++nt) {
      size_t boff = (size_t)(bn + nt * 16 + jl) * K + k0 + kg * 8;
      bf16x8 bhi = *(const bf16x8*)(WThi + boff);
      bf16x8 blo = *(const bf16x8*)(WTlo + boff);
      #pragma unroll
      for (int mt = 0; mt < 2; ++mt) {
        acc[mt][nt] = __builtin_amdgcn_mfma_f32_16x16x32_bf16(alo[mt], bhi, acc[mt][nt], 0, 0, 0);
        acc[mt][nt] = __builtin_amdgcn_mfma_f32_16x16x32_bf16(ahi[mt], blo, acc[mt][nt], 0, 0, 0);
        acc[mt][nt] = __builtin_amdgcn_mfma_f32_16x16x32_bf16(ahi[mt], bhi, acc[mt][nt], 0, 0, 0);
      }
    }
    __syncthreads();
  }
  // epilogue: C/D layout col=jl, row=kg*4+qi (verified)
  #pragma unroll
  for (int mt = 0; mt < 2; ++mt)
    #pragma unroll
    for (int nt = 0; nt < 4; ++nt)
      #pragma unroll
      for (int qi = 0; qi < 4; ++qi) {
        int m = bm + (w * 2 + mt) * 16 + kg * 4 + qi;
        int n = bn + nt * 16 + jl;
        float v = acc[mt][nt][qi];
        if (bias) v += bias[n];
        if (relu) v = fmaxf(v, 0.f);
        if (resid) v += resid[(size_t)m * N + n];
        out[(size_t)m * N + n] = v;
      }
}

// ---------------------------------------------------------------------------
// MFMA attention v5: 128 j-rows per block, sim staged in TWO 64-row chunks
// ([64][260] fp32 = 65 KB -> 2 blocks/CU, doubling occupancy vs v4).
// Single k-sweep keeps w2 traffic unchanged; acc stays in registers across
// chunk epilogues. Epilogue math per (r,c) identical to verified v4.
// KV is the merged [Mt][512] buffer: K = cols 0..255, V = cols 256..511.
// ---------------------------------------------------------------------------
template <int KN>
__global__ __launch_bounds__(256, 2) void attn5_kernel(
    const float* __restrict__ Qw, const float* __restrict__ KV,
    const int* __restrict__ nn,
    const float* __restrict__ b1, const __bf16* __restrict__ w2Thi,
    const __bf16* __restrict__ w2Tlo, const float* __restrict__ b2,
    const float* __restrict__ skip, float* __restrict__ out, int Tq, int Tt)
{
  constexpr int G  = 128 / KN;   // query rows per block
  constexpr int GC = 64 / KN;    // query rows per chunk
  constexpr int LD = 260;        // 2-way bank alias on C-store = free (m136)
  __shared__ float sim[64 * LD]; // 65 KB
  __shared__ int nns[128];
  int r0 = blockIdx.x * G;       // flat query row base
  int b = r0 / Tq;
  int tid = threadIdx.x;
  if (tid < 128) nns[tid] = nn[(size_t)r0 * KN + tid];
  __syncthreads();

  int w = tid >> 6, lane = tid & 63;
  int jl = lane & 15;
  int kg = lane >> 4;
  int nt0 = w * 4;
  const float* kvb = KV + (size_t)b * Tt * 512;

  f32x4 acc[8][4];
  #pragma unroll
  for (int m = 0; m < 8; ++m)
    #pragma unroll
    for (int n = 0; n < 4; ++n) acc[m][n] = (f32x4){0.f, 0.f, 0.f, 0.f};

  const float* qp[8];
  const float* kp[8];
  #pragma unroll
  for (int mt = 0; mt < 8; ++mt) {
    int jr = mt * 16 + jl;
    qp[mt] = Qw + (size_t)(r0 + jr / KN) * 256;
    kp[mt] = kvb + (size_t)nns[jr] * 512;
  }

  #pragma unroll
  for (int ks = 0; ks < 8; ++ks) {
    int c0 = ks * 32 + kg * 8;
    float4 b1a = *(const float4*)(b1 + c0);
    float4 b1b = *(const float4*)(b1 + c0 + 4);
    bf16x8 ahi[8], alo[8];
    #pragma unroll
    for (int mt = 0; mt < 8; ++mt) {
      float4 qa = *(const float4*)(qp[mt] + c0);
      float4 qb = *(const float4*)(qp[mt] + c0 + 4);
      float4 ka = *(const float4*)(kp[mt] + c0);
      float4 kb = *(const float4*)(kp[mt] + c0 + 4);
      float h[8];
      h[0] = fmaxf(qa.x - ka.x + b1a.x, 0.f);
      h[1] = fmaxf(qa.y - ka.y + b1a.y, 0.f);
      h[2] = fmaxf(qa.z - ka.z + b1a.z, 0.f);
      h[3] = fmaxf(qa.w - ka.w + b1a.w, 0.f);
      h[4] = fmaxf(qb.x - kb.x + b1b.x, 0.f);
      h[5] = fmaxf(qb.y - kb.y + b1b.y, 0.f);
      h[6] = fmaxf(qb.z - kb.z + b1b.z, 0.f);
      h[7] = fmaxf(qb.w - kb.w + b1b.w, 0.f);
      #pragma unroll
      for (int i = 0; i < 8; ++i) {
        __bf16 t0 = (__bf16)h[i];
        ahi[mt][i] = t0;
        alo[mt][i] = (__bf16)(h[i] - (float)t0);
      }
    }
    #pragma unroll
    for (int t = 0; t < 4; ++t) {
      size_t boff = (size_t)((nt0 + t) * 16 + jl) * 256 + c0;
      bf16x8 bhi = *(const bf16x8*)(w2Thi + boff);
      bf16x8 blo = *(const bf16x8*)(w2Tlo + boff);
      #pragma unroll
      for (int mt = 0; mt < 8; ++mt) {
        acc[mt][t] = __builtin_amdgcn_mfma_f32_16x16x32_bf16(alo[mt], bhi, acc[mt][t], 0, 0, 0);
        acc[mt][t] = __builtin_amdgcn_mfma_f32_16x16x32_bf16(ahi[mt], blo, acc[mt][t], 0, 0, 0);
        acc[mt][t] = __builtin_amdgcn_mfma_f32_16x16x32_bf16(ahi[mt], bhi, acc[mt][t], 0, 0, 0);
      }
    }
  }

  int c = tid;
  float bb2 = b2[c];
  const float* vbb = kvb + 256;   // V columns of merged KV
  #pragma unroll
  for (int ch = 0; ch < 2; ++ch) {
    if (ch) __syncthreads();       // prior chunk's epilogue reads done
    // store m-tiles [ch*4, ch*4+4) into sim rows [0,64)
    #pragma unroll
    for (int m2 = 0; m2 < 4; ++m2) {
      int mt = ch * 4 + m2;
      #pragma unroll
      for (int t = 0; t < 4; ++t)
        #pragma unroll
        for (int qi = 0; qi < 4; ++qi)
          sim[(m2 * 16 + kg * 4 + qi) * LD + (nt0 + t) * 16 + jl] = acc[mt][t][qi];
    }
    __syncthreads();
    // epilogue for the GC query rows of this chunk
    #pragma unroll
    for (int gg = 0; gg < GC; ++gg) {
      int jb_l = gg * KN;            // local sim row base
      int jb_g = ch * 64 + gg * KN;  // global j base (nns index)
      float m = -INFINITY;
      #pragma unroll 8
      for (int jj = 0; jj < KN; ++jj)
        m = fmaxf(m, sim[(jb_l + jj) * LD + c] + bb2);
      float ssum = 0.f, o = 0.f;
      #pragma unroll 8
      for (int jj = 0; jj < KN; ++jj) {
        float e = expf(sim[(jb_l + jj) * LD + c] + bb2 - m);
        ssum += e;
        o = fmaf(e, vbb[(size_t)nns[jb_g + jj] * 512 + c], o);
      }
      int r = r0 + ch * GC + gg;
      out[(size_t)r * 256 + c] = o / ssum + skip[(size_t)r * 256 + c];
    }
  }
}

// ---------------------------------------------------------------------------
// Final head
// ---------------------------------------------------------------------------
__global__ void gmean_kernel(const float* __restrict__ tok,
                             float* __restrict__ out, int Tt)
{
  int i = blockIdx.x * blockDim.x + threadIdx.x;
  if (i >= BB * CC) return;
  int b = i >> 8;
  int c = i & 255;
  float s = 0.f;
  for (int t = 0; t < Tt; ++t) s += tok[((size_t)b * Tt + t) * 256 + c];
  out[i] = s / (float)Tt;
}

__global__ void embbn_kernel(const float* __restrict__ x,
                             const float* __restrict__ g,
                             const float* __restrict__ bta,
                             float* __restrict__ y)
{
  int e = blockIdx.x * blockDim.x + threadIdx.x;
  if (e >= EE) return;
  float s = 0.f;
  for (int r = 0; r < BB; ++r) s += x[r * EE + e];
  float m = s / (float)BB;
  float vs = 0.f;
  for (int r = 0; r < BB; ++r) {
    float d = x[r * EE + e] - m;
    vs = fmaf(d, d, vs);
  }
  float rs = rsqrtf(vs / (float)BB + 1e-5f);
  for (int r = 0; r < BB; ++r) {
    float val = (x[r * EE + e] - m) * rs * g[e] + bta[e];
    y[r * EE + e] = fmaxf(val, 0.f);
  }
}

__global__ __launch_bounds__(256) void topk_norm_kernel(
    const float* __restrict__ gin, float* __restrict__ out)
{
  int b = blockIdx.x, tid = threadIdx.x, lane = tid & 63, wid = tid >> 6;
  __shared__ float vals[512];
  __shared__ float wv[4];
  __shared__ int wi[4];
  __shared__ float sh;
  float g0 = gin[b * 512 + tid];
  float g1 = gin[b * 512 + 256 + tid];
  vals[tid] = g0;
  vals[256 + tid] = g1;
  __syncthreads();
  for (int it = 0; it < 64; ++it) {
    float v = vals[tid];
    int ix = tid;
    float u = vals[256 + tid];
    if (u > v) { v = u; ix = 256 + tid; }
    #pragma unroll
    for (int off = 32; off > 0; off >>= 1) {
      float ov = __shfl_down(v, off);
      int oi = __shfl_down(ix, off);
      if (ov > v || (ov == v && oi < ix)) { v = ov; ix = oi; }
    }
    if (lane == 0) { wv[wid] = v; wi[wid] = ix; }
    __syncthreads();
    if (tid == 0) {
      float bv = wv[0]; int bi = wi[0];
      for (int w = 1; w < 4; ++w)
        if (wv[w] > bv || (wv[w] == bv && wi[w] < bi)) { bv = wv[w]; bi = wi[w]; }
      vals[bi] = -INFINITY;
      sh = bv;
    }
    __syncthreads();
  }
  float thr = sh;
  float m0 = (g0 >= thr) ? g0 : 0.f;
  float m1 = (g1 >= thr) ? g1 : 0.f;
  float ss = m0 * m0 + m1 * m1;
  #pragma unroll
  for (int off = 32; off > 0; off >>= 1) ss += __shfl_down(ss, off);
  if (lane == 0) wv[wid] = ss;
  __syncthreads();
  if (tid == 0) {
    float t = wv[0] + wv[1] + wv[2] + wv[3];
    sh = fmaxf(sqrtf(t), 1e-12f);
  }
  __syncthreads();
  float n = sh;
  out[b * 512 + tid] = m0 / n;
  out[b * 512 + 256 + tid] = m1 / n;
}

// ---------------------------------------------------------------------------
// Host orchestration
// ---------------------------------------------------------------------------
extern "C" void kernel_launch(void* const* d_in, const int* in_sizes, int n_in,
                              void* d_out, int out_size, void* d_ws, size_t ws_size,
                              hipStream_t stream)
{
  const float* tokens  = (const float*)d_in[0];
  const float* centers = (const float*)d_in[1];
  // d_in[2] = lrfs: dead in the reference
  const float* wq      = (const float*)d_in[3];
  const float* wkv     = (const float*)d_in[4];
  const float* mlp_w1  = (const float*)d_in[5];
  const float* mlp_b1  = (const float*)d_in[6];
  const float* mlp_w2  = (const float*)d_in[7];
  const float* mlp_b2  = (const float*)d_in[8];
  const float* bn1_g   = (const float*)d_in[9];
  const float* bn1_b   = (const float*)d_in[10];
  const float* bn2_g   = (const float*)d_in[11];
  const float* bn2_b   = (const float*)d_in[12];
  const float* att_w1  = (const float*)d_in[13];
  const float* att_b1  = (const float*)d_in[14];
  const float* att_w2  = (const float*)d_in[15];
  const float* att_b2  = (const float*)d_in[16];
  const float* emb_w   = (const float*)d_in[17];
  const float* emb_b   = (const float*)d_in[18];
  const float* embn_g  = (const float*)d_in[19];
  const float* embn_b  = (const float*)d_in[20];
  (void)in_sizes; (void)n_in; (void)out_size; (void)ws_size;

  char* ws = (char*)d_ws;
  size_t off = 0;
  auto alloc = [&](size_t bytes) -> void* {
    void* p = ws + off;
    off += (bytes + 255) & ~(size_t)255;
    return p;
  };
  const size_t tokMax  = (size_t)BB * 512 * CC * 4;   // 8 MB
  float* tokA     = (float*)alloc(tokMax);
  float* tokB     = (float*)alloc(tokMax);
  float* ctrA     = (float*)alloc((size_t)BB * 512 * 3 * 4);
  float* ctrB     = (float*)alloc((size_t)BB * 256 * 3 * 4);
  float* ctrC     = (float*)alloc((size_t)BB * 128 * 3 * 4);
  float* tokq_raw = (float*)alloc(tokMax);
  float* Qw1      = (float*)alloc(tokMax);
  float* KVbuf    = (float*)alloc((size_t)BB * 1024 * 512 * 4);  // 32 MB
  float* tq1      = (float*)alloc(tokMax);
  float* mlph     = (float*)alloc((size_t)BB * 512 * 512 * 4);
  float* WFq      = (float*)alloc((size_t)3 * CC * CC * 4);
  float* WFk      = (float*)alloc((size_t)3 * CC * CC * 4);
  __bf16* w2Thi   = (__bf16*)alloc((size_t)3 * CC * CC * 2);
  __bf16* w2Tlo   = (__bf16*)alloc((size_t)3 * CC * CC * 2);
  __bf16* wfqThi  = (__bf16*)alloc((size_t)3 * CC * CC * 2);
  __bf16* wfqTlo  = (__bf16*)alloc((size_t)3 * CC * CC * 2);
  __bf16* wkvThi  = (__bf16*)alloc((size_t)3 * 512 * CC * 2);  // [K|V] rows
  __bf16* wkvTlo  = (__bf16*)alloc((size_t)3 * 512 * CC * 2);
  __bf16* w1Thi   = (__bf16*)alloc((size_t)3 * CC * 512 * 2);
  __bf16* w1Tlo   = (__bf16*)alloc((size_t)3 * CC * 512 * 2);
  __bf16* wm2Thi  = (__bf16*)alloc((size_t)3 * 512 * CC * 2);
  __bf16* wm2Tlo  = (__bf16*)alloc((size_t)3 * 512 * CC * 2);
  int*   rep0     = (int*)alloc((size_t)BB * 512 * 4);
  int*   rep1     = (int*)alloc((size_t)BB * 256 * 4);
  int*   rep2     = (int*)alloc((size_t)BB * 128 * 4);
  int*   nnb      = (int*)alloc((size_t)BB * 512 * 64 * 4);
  float* bnpart   = (float*)alloc((size_t)64 * 512 * 4);
  float* bn1mean  = (float*)alloc(256 * 4);
  float* bn1rstd  = (float*)alloc(256 * 4);
  float* bn2mean  = (float*)alloc(256 * 4);
  float* bn2rstd  = (float*)alloc(256 * 4);
  float* gmeanb   = (float*)alloc((size_t)BB * CC * 4);
  float* gembb    = (float*)alloc((size_t)BB * EE * 4);
  float* grelub   = (float*)alloc((size_t)BB * EE * 4);

  const int NC[3] = {512, 256, 128};
  const int NN[3] = {16, 32, 64};
  int* reps[3] = {rep0, rep1, rep2};
  float* ctrq[3] = {ctrA, ctrB, ctrC};

  // One-time weight prep.
  for (int i = 0; i < 3; ++i) {
    gemm_kernel<<<dim3(4, 4), 256, 0, stream>>>(
        wq + (size_t)i * CC * CC, CC, att_w1 + (size_t)i * CC * CC, CC,
        nullptr, nullptr, WFq + (size_t)i * CC * CC, CC, CC, CC, 0);
    gemm_kernel<<<dim3(4, 4), 256, 0, stream>>>(
        wkv + (size_t)i * CC * 512, 512, att_w1 + (size_t)i * CC * CC, CC,
        nullptr, nullptr, WFk + (size_t)i * CC * CC, CC, CC, CC, 0);
  }
  split_w2_kernel<<<3 * 65536 / 256, 256, 0, stream>>>(att_w2, w2Thi, w2Tlo);
  for (int i = 0; i < 3; ++i) {
    int t1 = CC * CC;
    splitT_kernel<<<(t1 + 255) / 256, 256, 0, stream>>>(
        WFq + (size_t)i * CC * CC, CC, CC, CC,
        wfqThi + (size_t)i * t1, wfqTlo + (size_t)i * t1, t1);
    // merged KV weights [512][256]: rows 0..255 = folded-K, 256..511 = V
    splitT_kernel<<<(t1 + 255) / 256, 256, 0, stream>>>(
        WFk + (size_t)i * CC * CC, CC, CC, CC,
        wkvThi + (size_t)i * 512 * CC, wkvTlo + (size_t)i * 512 * CC, t1);
    splitT_kernel<<<(t1 + 255) / 256, 256, 0, stream>>>(
        wkv + (size_t)i * CC * 512 + CC, 512, CC, CC,
        wkvThi + (size_t)i * 512 * CC + t1, wkvTlo + (size_t)i * 512 * CC + t1, t1);
    int t2 = CC * 512;   // mlp_w1: K=256, N=512
    splitT_kernel<<<(t2 + 255) / 256, 256, 0, stream>>>(
        mlp_w1 + (size_t)i * t2, 512, CC, 512,
        w1Thi + (size_t)i * t2, w1Tlo + (size_t)i * t2, t2);
    // mlp_w2: K=512, N=256
    splitT_kernel<<<(t2 + 255) / 256, 256, 0, stream>>>(
        mlp_w2 + (size_t)i * t2, CC, 512, CC,
        wm2Thi + (size_t)i * t2, wm2Tlo + (size_t)i * t2, t2);
  }

  const float* cur_tok = tokens;
  const float* cur_ctr = centers;
  int curTt = TT0;
  float* tok_bufs[2] = {tokA, tokB};

  // fps0 (on raw centers) is co-scheduled with the stage-0 KV projection.
  for (int i = 0; i < 3; ++i) {
    int Tq = NC[i], Kn = NN[i], Tt = curTt;
    float* ctr_q = ctrq[i];
    float* tok_next = tok_bufs[i & 1];
    int M = BB * Tq;
    int Mt = BB * Tt;
    int* rep = reps[i];

    const float *b1m = nullptr, *b1r = nullptr, *b1g = nullptr, *b1b = nullptr;

    if (i == 0) {
      // KV0 projection (A=tokens, no BN) + co-scheduled fps0
      gemm_mfma_kernel<16><<<dim3(512 / 64 + 1, Mt / 128), 256, 0, stream>>>(
          tokens, CC, wkvThi, wkvTlo, nullptr, nullptr, KVbuf,
          Mt, 512, CC, 0, nullptr, nullptr, nullptr, nullptr,
          512 / 64, centers, 1024, 512, rep0);
    }

    // gathers (need rep_i) + kNN
    {
      int tot = BB * Tq * 3;
      gather_rows_kernel<<<(tot + 255) / 256, 256, 0, stream>>>(
          cur_ctr, rep, ctr_q, Tq, Tt, 3, tot);
    }
    {
      int tot = M * CC;
      gather_rows_kernel<<<(tot + 255) / 256, 256, 0, stream>>>(
          cur_tok, rep, tokq_raw, Tq, Tt, CC, tot);
    }
    knn_kernel<<<M, 256, 0, stream>>>(ctr_q, cur_ctr, Tq, Tt, Kn, nnb);

    if (i > 0) {
      // BN1 stats over concat(query, target); apply fused into GEMMs
      bn_stats_kernel<<<64, 256, 0, stream>>>(tokq_raw, M, cur_tok, Mt, bnpart, 64);
      bn_finalize_kernel<<<1, 256, 0, stream>>>(bnpart, 64, M + Mt, bn1mean, bn1rstd);
      b1m = bn1mean; b1r = bn1rstd; b1g = bn1_g + i * CC; b1b = bn1_b + i * CC;
      // KV projection with fused BN1; stage 1 also co-schedules fps2 (ctrB
      // is ready from this stage's center gather).
      if (i == 1)
        gemm_mfma_kernel<4><<<dim3(512 / 64 + 1, Mt / 128), 256, 0, stream>>>(
            cur_tok, CC, wkvThi + (size_t)i * 512 * CC, wkvTlo + (size_t)i * 512 * CC,
            nullptr, nullptr, KVbuf, Mt, 512, CC, 0, b1m, b1r, b1g, b1b,
            512 / 64, ctrB, 256, 128, rep2);
      else
        gemm_mfma_kernel<4><<<dim3(512 / 64, Mt / 128), 256, 0, stream>>>(
            cur_tok, CC, wkvThi + (size_t)i * 512 * CC, wkvTlo + (size_t)i * 512 * CC,
            nullptr, nullptr, KVbuf, Mt, 512, CC, 0, b1m, b1r, b1g, b1b,
            512 / 64, nullptr, 0, 0, nullptr);
    }

    // Q projection (folded weights, fused BN1)
    gemm_mfma_kernel<4><<<dim3(CC / 64, M / 128), 256, 0, stream>>>(
        tokq_raw, CC, wfqThi + (size_t)i * CC * CC, wfqTlo + (size_t)i * CC * CC,
        nullptr, nullptr, Qw1, M, CC, CC, 0, b1m, b1r, b1g, b1b,
        CC / 64, nullptr, 0, 0, nullptr);

    // Fused neighborhood attention via MFMA, 128 rows/block (+ skip)
    if (Kn == 16)
      attn5_kernel<16><<<dim3(M / 8), 256, 0, stream>>>(
          Qw1, KVbuf, nnb, att_b1 + i * CC,
          w2Thi + (size_t)i * CC * CC, w2Tlo + (size_t)i * CC * CC,
          att_b2 + i * CC, tokq_raw, tq1, Tq, Tt);
    else if (Kn == 32)
      attn5_kernel<32><<<dim3(M / 4), 256, 0, stream>>>(
          Qw1, KVbuf, nnb, att_b1 + i * CC,
          w2Thi + (size_t)i * CC * CC, w2Tlo + (size_t)i * CC * CC,
          att_b2 + i * CC, tokq_raw, tq1, Tq, Tt);
    else
      attn5_kernel<64><<<dim3(M / 2), 256, 0, stream>>>(
          Qw1, KVbuf, nnb, att_b1 + i * CC,
          w2Thi + (size_t)i * CC * CC, w2Tlo + (size_t)i * CC * CC,
          att_b2 + i * CC, tokq_raw, tq1, Tq, Tt);

    // BN2 stats + MLP (+ skip2); BN2 fused into MLP1. Stage 0's MLP1 also
    // co-schedules fps1 (ctrA ready from this stage's center gather).
    bn_stats_kernel<<<64, 256, 0, stream>>>(tq1, M, tq1, 0, bnpart, 64);
    bn_finalize_kernel<<<1, 256, 0, stream>>>(bnpart, 64, M, bn2mean, bn2rstd);
    if (i == 0)
      gemm_mfma_kernel<8><<<dim3(512 / 64 + 1, M / 128), 256, 0, stream>>>(
          tq1, CC, w1Thi + (size_t)i * CC * 512, w1Tlo + (size_t)i * CC * 512,
          mlp_b1 + i * 512, nullptr, mlph, M, 512, CC, 1,
          bn2mean, bn2rstd, bn2_g + i * CC, bn2_b + i * CC,
          512 / 64, ctrA, 512, 256, rep1);
    else
      gemm_mfma_kernel<4><<<dim3(512 / 64, M / 128), 256, 0, stream>>>(
          tq1, CC, w1Thi + (size_t)i * CC * 512, w1Tlo + (size_t)i * CC * 512,
          mlp_b1 + i * 512, nullptr, mlph, M, 512, CC, 1,
          bn2mean, bn2rstd, bn2_g + i * CC, bn2_b + i * CC,
          512 / 64, nullptr, 0, 0, nullptr);
    gemm_mfma_kernel<4><<<dim3(CC / 64, M / 128), 256, 0, stream>>>(
        mlph, 512, wm2Thi + (size_t)i * 512 * CC, wm2Tlo + (size_t)i * 512 * CC,
        mlp_b2 + i * CC, tq1, tok_next, M, CC, 512, 0,
        nullptr, nullptr, nullptr, nullptr,
        CC / 64, nullptr, 0, 0, nullptr);

    cur_tok = tok_next;
    cur_ctr = ctr_q;
    curTt = Tq;
  }

  // Final head
  gmean_kernel<<<(BB * CC + 255) / 256, 256, 0, stream>>>(cur_tok, gmeanb, curTt);
  gemm_kernel<<<dim3(EE / 64, 1), 256, 0, stream>>>(
      gmeanb, CC, emb_w, EE, emb_b, nullptr, gembb, BB, EE, CC, 0);
  embbn_kernel<<<2, 256, 0, stream>>>(gembb, embn_g, embn_b, grelub);
  topk_norm_kernel<<<BB, 256, 0, stream>>>(grelub, (float*)d_out);
}

// Round 16
// 1604.791 us; speedup vs baseline: 1.2334x; 1.1427x over previous
//
#include <hip/hip_runtime.h>
#include <cstdint>
#include <cmath>

// Problem constants
static constexpr int BB = 16;    // batch
static constexpr int TT0 = 1024; // initial tokens
static constexpr int CC = 256;   // channels
static constexpr int EE = 512;   // embedding

typedef __bf16 bf16x8 __attribute__((ext_vector_type(8)));
typedef float  f32x4  __attribute__((ext_vector_type(4)));

// ---------------------------------------------------------------------------
// FPS body v5 (verified rounds 12/13/15): one 64-lane wave per batch.
// ---------------------------------------------------------------------------
template <int NPL>
__device__ void fps_body(float4* sp, const float* __restrict__ ctr,
                         int Tt, int Ksel, int* __restrict__ rep,
                         int b, int lane)
{
  const float* base = ctr + (size_t)b * Tt * 3;
  float x[NPL], y[NPL], z[NPL], d[NPL];
  #pragma unroll
  for (int j = 0; j < NPL; ++j) {
    int idx = lane * NPL + j;
    x[j] = base[idx * 3 + 0];
    y[j] = base[idx * 3 + 1];
    z[j] = base[idx * 3 + 2];
    d[j] = INFINITY;
    sp[idx] = make_float4(x[j], y[j], z[j], 0.f);
  }
  int cur = 0;
  for (int s = 0; s < Ksel; ++s) {
    if (lane == 0) rep[b * Ksel + s] = cur;
    float4 cpt = sp[cur];  // uniform address -> broadcast
    unsigned long long key = 0ull;
    #pragma unroll
    for (int j = 0; j < NPL; ++j) {
      float dx = __fsub_rn(x[j], cpt.x);
      float dy = __fsub_rn(y[j], cpt.y);
      float dz = __fsub_rn(z[j], cpt.z);
      float dist = __fadd_rn(__fadd_rn(__fmul_rn(dx, dx), __fmul_rn(dy, dy)),
                             __fmul_rn(dz, dz));
      float nd = fminf(d[j], dist);
      d[j] = nd;
      unsigned long long kj =
          ((unsigned long long)__float_as_uint(nd) << 32) |
          (unsigned)(0xFFFFFFFFu - (unsigned)(lane * NPL + j));
      key = (kj > key) ? kj : key;
    }
    // d >= 0 finite: float order == bit order; no NaN/-0 possible.
    float ld = __uint_as_float((unsigned)(key >> 32));
    float rm = ld;
    {
      int t;
      t = __builtin_amdgcn_mov_dpp(__float_as_int(rm), 0x121, 0xf, 0xf, false);
      rm = fmaxf(rm, __int_as_float(t));
      t = __builtin_amdgcn_mov_dpp(__float_as_int(rm), 0x122, 0xf, 0xf, false);
      rm = fmaxf(rm, __int_as_float(t));
      t = __builtin_amdgcn_mov_dpp(__float_as_int(rm), 0x124, 0xf, 0xf, false);
      rm = fmaxf(rm, __int_as_float(t));
      t = __builtin_amdgcn_mov_dpp(__float_as_int(rm), 0x128, 0xf, 0xf, false);
      rm = fmaxf(rm, __int_as_float(t));
    }
    float r0 = __uint_as_float((unsigned)__builtin_amdgcn_readlane(__float_as_int(rm), 0));
    float r1 = __uint_as_float((unsigned)__builtin_amdgcn_readlane(__float_as_int(rm), 16));
    float r2 = __uint_as_float((unsigned)__builtin_amdgcn_readlane(__float_as_int(rm), 32));
    float r3 = __uint_as_float((unsigned)__builtin_amdgcn_readlane(__float_as_int(rm), 48));
    float gm = fmaxf(fmaxf(r0, r1), fmaxf(r2, r3));
    unsigned long long mask = __ballot(ld == gm);
    int wl = __ffsll(mask) - 1;
    unsigned lowkey = (unsigned)__builtin_amdgcn_readlane((int)(unsigned)key, wl);
    cur = (int)(0xFFFFFFFFu - lowkey);
  }
}

// ---------------------------------------------------------------------------
// kNN v2: one 64-lane wave per query row (4 rows per 256-thr block), all
// state in registers, ZERO barriers/LDS (fps-v5 pattern).
//  - d2 computed with the byte-identical _rn sequence (indices bit-exact)
//  - key[j] = (monotone(d2) << 32) | t; u64 MIN = lexicographic (d2, t) min
//    == lax.top_k(-d2,k) order. Monotone map u^=(u>>31)?0xFFFFFFFF:0x80000000
//    is strictly order-preserving; d2 never -0.0 (IEEE x-x = +0.0), no NaN.
//  - cross-lane min: DPP row_ror u32-min + readlane + ballot/ffs/readlane;
//    lane-major t order => lowest candidate lane holds smallest index.
//  - invalidation: winner lane sets its key to ~0 via unrolled compare.
// ---------------------------------------------------------------------------
template <int NPL2>
__global__ __launch_bounds__(256) void knn_wave_kernel(
    const float* __restrict__ cq, const float* __restrict__ ct,
    int Tq, int Tt, int Kn, int* __restrict__ nn)
{
  int wid = threadIdx.x >> 6, lane = threadIdx.x & 63;
  int r = blockIdx.x * 4 + wid;   // query row (M % 4 == 0 always)
  int b = r / Tq;
  const float* tb = ct + (size_t)b * Tt * 3;
  float qx = cq[(size_t)r * 3 + 0];
  float qy = cq[(size_t)r * 3 + 1];
  float qz = cq[(size_t)r * 3 + 2];
  float sq = __fadd_rn(__fadd_rn(__fmul_rn(qx, qx), __fmul_rn(qy, qy)),
                       __fmul_rn(qz, qz));
  unsigned long long key[NPL2];
  #pragma unroll
  for (int j = 0; j < NPL2; ++j) {
    int t = lane * NPL2 + j;
    float tx = tb[t * 3 + 0], ty = tb[t * 3 + 1], tz = tb[t * 3 + 2];
    float st = __fadd_rn(__fadd_rn(__fmul_rn(tx, tx), __fmul_rn(ty, ty)),
                         __fmul_rn(tz, tz));
    float dot = __fadd_rn(__fadd_rn(__fmul_rn(qx, tx), __fmul_rn(qy, ty)),
                          __fmul_rn(qz, tz));
    float d2 = __fsub_rn(__fadd_rn(sq, st), __fmul_rn(2.0f, dot));
    unsigned ub = __float_as_uint(d2);
    ub ^= (ub >> 31) ? 0xFFFFFFFFu : 0x80000000u;   // monotone map
    key[j] = ((unsigned long long)ub << 32) | (unsigned)t;
  }
  for (int k = 0; k < Kn; ++k) {
    unsigned long long lmin = ~0ull;
    #pragma unroll
    for (int j = 0; j < NPL2; ++j) lmin = (key[j] < lmin) ? key[j] : lmin;
    unsigned md = (unsigned)(lmin >> 32);
    unsigned rm = md;
    {
      unsigned t;
      t = (unsigned)__builtin_amdgcn_mov_dpp((int)rm, 0x121, 0xf, 0xf, false);
      rm = (t < rm) ? t : rm;
      t = (unsigned)__builtin_amdgcn_mov_dpp((int)rm, 0x122, 0xf, 0xf, false);
      rm = (t < rm) ? t : rm;
      t = (unsigned)__builtin_amdgcn_mov_dpp((int)rm, 0x124, 0xf, 0xf, false);
      rm = (t < rm) ? t : rm;
      t = (unsigned)__builtin_amdgcn_mov_dpp((int)rm, 0x128, 0xf, 0xf, false);
      rm = (t < rm) ? t : rm;
    }
    unsigned r0 = (unsigned)__builtin_amdgcn_readlane((int)rm, 0);
    unsigned r1 = (unsigned)__builtin_amdgcn_readlane((int)rm, 16);
    unsigned r2 = (unsigned)__builtin_amdgcn_readlane((int)rm, 32);
    unsigned r3 = (unsigned)__builtin_amdgcn_readlane((int)rm, 48);
    unsigned g01 = (r0 < r1) ? r0 : r1;
    unsigned g23 = (r2 < r3) ? r2 : r3;
    unsigned gmin = (g01 < g23) ? g01 : g23;
    unsigned long long mask = __ballot(md == gmin);
    int wl = __ffsll(mask) - 1;
    int wt = __builtin_amdgcn_readlane((int)(unsigned)lmin, wl);
    if (lane == 0) nn[(size_t)r * Kn + k] = wt;
    #pragma unroll
    for (int j = 0; j < NPL2; ++j)
      if (lane * NPL2 + j == wt) key[j] = ~0ull;
  }
}

// ---------------------------------------------------------------------------
// Row gather
// ---------------------------------------------------------------------------
__global__ void gather_rows_kernel(
    const float* __restrict__ src, const int* __restrict__ idx,
    float* __restrict__ dst, int Tq, int Tt, int D, int total)
{
  int i = blockIdx.x * blockDim.x + threadIdx.x;
  if (i >= total) return;
  int d = i % D;
  int q = (i / D) % Tq;
  int b = i / (D * Tq);
  int s = idx[b * Tq + q];
  dst[i] = src[((size_t)b * Tt + s) * D + d];
}

// ---------------------------------------------------------------------------
// BatchNorm stats (apply is fused into GEMM A-staging)
// ---------------------------------------------------------------------------
__global__ __launch_bounds__(256) void bn_stats_kernel(
    const float* __restrict__ x1, int R1, const float* __restrict__ x2, int R2,
    float* __restrict__ part, int nch)
{
  int c = threadIdx.x;
  int chunk = blockIdx.x;
  int R = R1 + R2;
  int per = (R + nch - 1) / nch;
  int r0 = chunk * per;
  int r1 = min(r0 + per, R);
  float s = 0.f, ss = 0.f;
  for (int r = r0; r < r1; ++r) {
    float v = (r < R1) ? x1[(size_t)r * 256 + c] : x2[(size_t)(r - R1) * 256 + c];
    s += v;
    ss = fmaf(v, v, ss);
  }
  part[(size_t)chunk * 512 + c] = s;
  part[(size_t)chunk * 512 + 256 + c] = ss;
}

__global__ __launch_bounds__(256) void bn_finalize_kernel(
    const float* __restrict__ part, int nch, int R,
    float* __restrict__ mean, float* __restrict__ rstd)
{
  int c = threadIdx.x;
  float s = 0.f, ss = 0.f;
  for (int k = 0; k < nch; ++k) {
    s += part[(size_t)k * 512 + c];
    ss += part[(size_t)k * 512 + 256 + c];
  }
  float m = s / (float)R;
  float v = ss / (float)R - m * m;
  if (v < 0.f) v = 0.f;
  mean[c] = m;
  rstd[c] = rsqrtf(v + 1e-5f);
}

// ---------------------------------------------------------------------------
// fp32 tiled GEMM (kept for small prep/emb GEMMs)
// ---------------------------------------------------------------------------
__global__ __launch_bounds__(256) void gemm_kernel(
    const float* __restrict__ A, int lda,
    const float* __restrict__ W, int ldw,
    const float* __restrict__ bias, const float* __restrict__ resid,
    float* __restrict__ out, int M, int N, int K, int relu)
{
  __shared__ float As[32][68];
  __shared__ float Bs[32][68];
  int bm = blockIdx.y * 64;
  int bn = blockIdx.x * 64;
  int tid = threadIdx.x;
  int tx = tid & 15, ty = tid >> 4;
  int arow = tid >> 3;          // 0..31
  int ak = (tid & 7) * 4;       // 0,4,...,28
  int wk = tid >> 4;            // 0..15
  int wn = (tid & 15) * 4;      // 0..60
  float acc[4][4] = {{0.f}};
  for (int k0 = 0; k0 < K; k0 += 32) {
    #pragma unroll
    for (int h = 0; h < 2; ++h) {
      int row = bm + arow + h * 32;
      float4 a = (row < M)
          ? *(const float4*)&A[(size_t)row * lda + k0 + ak]
          : make_float4(0.f, 0.f, 0.f, 0.f);
      As[ak + 0][arow + h * 32] = a.x;
      As[ak + 1][arow + h * 32] = a.y;
      As[ak + 2][arow + h * 32] = a.z;
      As[ak + 3][arow + h * 32] = a.w;
    }
    #pragma unroll
    for (int h = 0; h < 2; ++h) {
      int krow = k0 + wk + h * 16;
      *(float4*)&Bs[wk + h * 16][wn] =
          *(const float4*)&W[(size_t)krow * ldw + bn + wn];
    }
    __syncthreads();
    #pragma unroll
    for (int k = 0; k < 32; ++k) {
      float4 a = *(const float4*)&As[k][ty * 4];
      float4 b = *(const float4*)&Bs[k][tx * 4];
      float av[4] = {a.x, a.y, a.z, a.w};
      float bv[4] = {b.x, b.y, b.z, b.w};
      #pragma unroll
      for (int i = 0; i < 4; ++i)
        #pragma unroll
        for (int j = 0; j < 4; ++j)
          acc[i][j] = fmaf(av[i], bv[j], acc[i][j]);
    }
    __syncthreads();
  }
  #pragma unroll
  for (int i = 0; i < 4; ++i) {
    int m = bm + ty * 4 + i;
    if (m >= M) continue;
    #pragma unroll
    for (int j = 0; j < 4; ++j) {
      int n = bn + tx * 4 + j;
      float v = acc[i][j];
      if (bias) v += bias[n];
      if (relu) v = fmaxf(v, 0.f);
      if (resid) v += resid[(size_t)m * N + n];
      out[(size_t)m * N + n] = v;
    }
  }
}

// ---------------------------------------------------------------------------
// Generic weight split+transpose: src f32 [K][N] (row stride ldw) ->
// dst bf16 hi/lo [N][K].
// ---------------------------------------------------------------------------
__global__ void splitT_kernel(
    const float* __restrict__ src, int ldw, int K, int N,
    __bf16* __restrict__ hi, __bf16* __restrict__ lo, int total)
{
  int i = blockIdx.x * blockDim.x + threadIdx.x;
  if (i >= total) return;
  int n = i / K;
  int k = i - n * K;
  float v = src[(size_t)k * ldw + n];
  __bf16 h = (__bf16)v;
  hi[i] = h;
  lo[i] = (__bf16)(v - (float)h);
}

// ---------------------------------------------------------------------------
// w2 transpose + bf16 hi/lo split (attn): w2[3][c][c'] f32 -> [3][c'][c]
// ---------------------------------------------------------------------------
__global__ __launch_bounds__(256) void split_w2_kernel(
    const float* __restrict__ w2, __bf16* __restrict__ hi,
    __bf16* __restrict__ lo)
{
  int i = blockIdx.x * 256 + threadIdx.x;   // over 3*65536
  int s = i >> 16;
  int e = i & 65535;
  int cp = e >> 8;   // c' (row of transposed)
  int cc = e & 255;  // c
  float v = w2[((size_t)s << 16) + cc * 256 + cp];
  __bf16 h = (__bf16)v;
  hi[i] = h;
  lo[i] = (__bf16)(v - (float)h);
}

// ---------------------------------------------------------------------------
// MFMA GEMM + optional fused BN on A + optional co-scheduled FPS blocks.
//   gemm blocks: blockIdx.x <  nbx  (BM=128, BN=64, BK=32, 256 thr)
//   fps  blocks: blockIdx.x == nbx && blockIdx.y < BB (one wave each; the
//                fps LDS scratch overlays the gemm As buffer; no barriers on
//                the fps path so divergent block paths are safe)
// Requires M%128==0, N%64==0, K%32==0, and gridDim.y >= BB when fps fused.
// ---------------------------------------------------------------------------
template <int NPL>
__global__ __launch_bounds__(256) void gemm_mfma_kernel(
    const float* __restrict__ A, int lda,
    const __bf16* __restrict__ WThi, const __bf16* __restrict__ WTlo,
    const float* __restrict__ bias, const float* __restrict__ resid,
    float* __restrict__ out, int M, int N, int K, int relu,
    const float* __restrict__ bnm, const float* __restrict__ bnr,
    const float* __restrict__ bng, const float* __restrict__ bnb,
    int nbx,
    const float* __restrict__ fps_ctr, int fps_Tt, int fps_Ksel,
    int* __restrict__ fps_rep)
{
  __shared__ __align__(16) float As[128 * 36];
  if ((int)blockIdx.x >= nbx) {
    // co-scheduled FPS path
    if (fps_rep == nullptr || (int)blockIdx.y >= BB) return;
    if ((int)threadIdx.x >= 64) return;
    fps_body<NPL>((float4*)As, fps_ctr, fps_Tt, fps_Ksel, fps_rep,
                  blockIdx.y, threadIdx.x);
    return;
  }
  int bm = blockIdx.y * 128;
  int bn = blockIdx.x * 64;
  int tid = threadIdx.x;
  int w = tid >> 6, lane = tid & 63;
  int jl = lane & 15;   // fragment row/col index
  int kg = lane >> 4;   // k-chunk group (8 elems)

  f32x4 acc[2][4];
  #pragma unroll
  for (int mt = 0; mt < 2; ++mt)
    #pragma unroll
    for (int nt = 0; nt < 4; ++nt) acc[mt][nt] = (f32x4){0.f, 0.f, 0.f, 0.f};

  for (int k0 = 0; k0 < K; k0 += 32) {
    // stage A tile [128][32] -> LDS [128][36], optional fused BN
    #pragma unroll
    for (int f = 0; f < 4; ++f) {
      int fi = tid + f * 256;       // float4 index 0..1023
      int row = fi >> 3, c4 = fi & 7;
      float4 v = *(const float4*)&A[(size_t)(bm + row) * lda + k0 + c4 * 4];
      if (bnm) {
        int kk = k0 + c4 * 4;
        float4 m4 = *(const float4*)&bnm[kk];
        float4 r4 = *(const float4*)&bnr[kk];
        float4 g4 = *(const float4*)&bng[kk];
        float4 b4 = *(const float4*)&bnb[kk];
        v.x = (v.x - m4.x) * r4.x * g4.x + b4.x;
        v.y = (v.y - m4.y) * r4.y * g4.y + b4.y;
        v.z = (v.z - m4.z) * r4.z * g4.z + b4.z;
        v.w = (v.w - m4.w) * r4.w * g4.w + b4.w;
      }
      *(float4*)&As[row * 36 + c4 * 4] = v;
    }
    __syncthreads();
    // A fragments (2 m-tiles), hi/lo convert
    bf16x8 ahi[2], alo[2];
    #pragma unroll
    for (int mt = 0; mt < 2; ++mt) {
      int row = (w * 2 + mt) * 16 + jl;
      float4 a0 = *(const float4*)&As[row * 36 + kg * 8];
      float4 a1 = *(const float4*)&As[row * 36 + kg * 8 + 4];
      float hv[8] = {a0.x, a0.y, a0.z, a0.w, a1.x, a1.y, a1.z, a1.w};
      #pragma unroll
      for (int i = 0; i < 8; ++i) {
        __bf16 t0 = (__bf16)hv[i];
        ahi[mt][i] = t0;
        alo[mt][i] = (__bf16)(hv[i] - (float)t0);
      }
    }
    #pragma unroll
    for (int nt = 0; nt < 4; ++nt) {
      size_t boff = (size_t)(bn + nt * 16 + jl) * K + k0 + kg * 8;
      bf16x8 bhi = *(const bf16x8*)(WThi + boff);
      bf16x8 blo = *(const bf16x8*)(WTlo + boff);
      #pragma unroll
      for (int mt = 0; mt < 2; ++mt) {
        acc[mt][nt] = __builtin_amdgcn_mfma_f32_16x16x32_bf16(alo[mt], bhi, acc[mt][nt], 0, 0, 0);
        acc[mt][nt] = __builtin_amdgcn_mfma_f32_16x16x32_bf16(ahi[mt], blo, acc[mt][nt], 0, 0, 0);
        acc[mt][nt] = __builtin_amdgcn_mfma_f32_16x16x32_bf16(ahi[mt], bhi, acc[mt][nt], 0, 0, 0);
      }
    }
    __syncthreads();
  }
  // epilogue: C/D layout col=jl, row=kg*4+qi (verified)
  #pragma unroll
  for (int mt = 0; mt < 2; ++mt)
    #pragma unroll
    for (int nt = 0; nt < 4; ++nt)
      #pragma unroll
      for (int qi = 0; qi < 4; ++qi) {
        int m = bm + (w * 2 + mt) * 16 + kg * 4 + qi;
        int n = bn + nt * 16 + jl;
        float v = acc[mt][nt][qi];
        if (bias) v += bias[n];
        if (relu) v = fmaxf(v, 0.f);
        if (resid) v += resid[(size_t)m * N + n];
        out[(size_t)m * N + n] = v;
      }
}

// ---------------------------------------------------------------------------
// MFMA attention v5 (verified round 15): 128 j-rows per block, sim staged in
// two 64-row chunks ([64][260] = 65 KB -> 2 blocks/CU).
// KV is the merged [Mt][512] buffer: K = cols 0..255, V = cols 256..511.
// ---------------------------------------------------------------------------
template <int KN>
__global__ __launch_bounds__(256, 2) void attn5_kernel(
    const float* __restrict__ Qw, const float* __restrict__ KV,
    const int* __restrict__ nn,
    const float* __restrict__ b1, const __bf16* __restrict__ w2Thi,
    const __bf16* __restrict__ w2Tlo, const float* __restrict__ b2,
    const float* __restrict__ skip, float* __restrict__ out, int Tq, int Tt)
{
  constexpr int G  = 128 / KN;   // query rows per block
  constexpr int GC = 64 / KN;    // query rows per chunk
  constexpr int LD = 260;        // 2-way bank alias on C-store = free (m136)
  __shared__ float sim[64 * LD]; // 65 KB
  __shared__ int nns[128];
  int r0 = blockIdx.x * G;       // flat query row base
  int b = r0 / Tq;
  int tid = threadIdx.x;
  if (tid < 128) nns[tid] = nn[(size_t)r0 * KN + tid];
  __syncthreads();

  int w = tid >> 6, lane = tid & 63;
  int jl = lane & 15;
  int kg = lane >> 4;
  int nt0 = w * 4;
  const float* kvb = KV + (size_t)b * Tt * 512;

  f32x4 acc[8][4];
  #pragma unroll
  for (int m = 0; m < 8; ++m)
    #pragma unroll
    for (int n = 0; n < 4; ++n) acc[m][n] = (f32x4){0.f, 0.f, 0.f, 0.f};

  const float* qp[8];
  const float* kp[8];
  #pragma unroll
  for (int mt = 0; mt < 8; ++mt) {
    int jr = mt * 16 + jl;
    qp[mt] = Qw + (size_t)(r0 + jr / KN) * 256;
    kp[mt] = kvb + (size_t)nns[jr] * 512;
  }

  #pragma unroll
  for (int ks = 0; ks < 8; ++ks) {
    int c0 = ks * 32 + kg * 8;
    float4 b1a = *(const float4*)(b1 + c0);
    float4 b1b = *(const float4*)(b1 + c0 + 4);
    bf16x8 ahi[8], alo[8];
    #pragma unroll
    for (int mt = 0; mt < 8; ++mt) {
      float4 qa = *(const float4*)(qp[mt] + c0);
      float4 qb = *(const float4*)(qp[mt] + c0 + 4);
      float4 ka = *(const float4*)(kp[mt] + c0);
      float4 kb = *(const float4*)(kp[mt] + c0 + 4);
      float h[8];
      h[0] = fmaxf(qa.x - ka.x + b1a.x, 0.f);
      h[1] = fmaxf(qa.y - ka.y + b1a.y, 0.f);
      h[2] = fmaxf(qa.z - ka.z + b1a.z, 0.f);
      h[3] = fmaxf(qa.w - ka.w + b1a.w, 0.f);
      h[4] = fmaxf(qb.x - kb.x + b1b.x, 0.f);
      h[5] = fmaxf(qb.y - kb.y + b1b.y, 0.f);
      h[6] = fmaxf(qb.z - kb.z + b1b.z, 0.f);
      h[7] = fmaxf(qb.w - kb.w + b1b.w, 0.f);
      #pragma unroll
      for (int i = 0; i < 8; ++i) {
        __bf16 t0 = (__bf16)h[i];
        ahi[mt][i] = t0;
        alo[mt][i] = (__bf16)(h[i] - (float)t0);
      }
    }
    #pragma unroll
    for (int t = 0; t < 4; ++t) {
      size_t boff = (size_t)((nt0 + t) * 16 + jl) * 256 + c0;
      bf16x8 bhi = *(const bf16x8*)(w2Thi + boff);
      bf16x8 blo = *(const bf16x8*)(w2Tlo + boff);
      #pragma unroll
      for (int mt = 0; mt < 8; ++mt) {
        acc[mt][t] = __builtin_amdgcn_mfma_f32_16x16x32_bf16(alo[mt], bhi, acc[mt][t], 0, 0, 0);
        acc[mt][t] = __builtin_amdgcn_mfma_f32_16x16x32_bf16(ahi[mt], blo, acc[mt][t], 0, 0, 0);
        acc[mt][t] = __builtin_amdgcn_mfma_f32_16x16x32_bf16(ahi[mt], bhi, acc[mt][t], 0, 0, 0);
      }
    }
  }

  int c = tid;
  float bb2 = b2[c];
  const float* vbb = kvb + 256;   // V columns of merged KV
  #pragma unroll
  for (int ch = 0; ch < 2; ++ch) {
    if (ch) __syncthreads();       // prior chunk's epilogue reads done
    #pragma unroll
    for (int m2 = 0; m2 < 4; ++m2) {
      int mt = ch * 4 + m2;
      #pragma unroll
      for (int t = 0; t < 4; ++t)
        #pragma unroll
        for (int qi = 0; qi < 4; ++qi)
          sim[(m2 * 16 + kg * 4 + qi) * LD + (nt0 + t) * 16 + jl] = acc[mt][t][qi];
    }
    __syncthreads();
    #pragma unroll
    for (int gg = 0; gg < GC; ++gg) {
      int jb_l = gg * KN;            // local sim row base
      int jb_g = ch * 64 + gg * KN;  // global j base (nns index)
      float m = -INFINITY;
      #pragma unroll 8
      for (int jj = 0; jj < KN; ++jj)
        m = fmaxf(m, sim[(jb_l + jj) * LD + c] + bb2);
      float ssum = 0.f, o = 0.f;
      #pragma unroll 8
      for (int jj = 0; jj < KN; ++jj) {
        float e = expf(sim[(jb_l + jj) * LD + c] + bb2 - m);
        ssum += e;
        o = fmaf(e, vbb[(size_t)nns[jb_g + jj] * 512 + c], o);
      }
      int r = r0 + ch * GC + gg;
      out[(size_t)r * 256 + c] = o / ssum + skip[(size_t)r * 256 + c];
    }
  }
}

// ---------------------------------------------------------------------------
// Final head
// ---------------------------------------------------------------------------
__global__ void gmean_kernel(const float* __restrict__ tok,
                             float* __restrict__ out, int Tt)
{
  int i = blockIdx.x * blockDim.x + threadIdx.x;
  if (i >= BB * CC) return;
  int b = i >> 8;
  int c = i & 255;
  float s = 0.f;
  for (int t = 0; t < Tt; ++t) s += tok[((size_t)b * Tt + t) * 256 + c];
  out[i] = s / (float)Tt;
}

__global__ void embbn_kernel(const float* __restrict__ x,
                             const float* __restrict__ g,
                             const float* __restrict__ bta,
                             float* __restrict__ y)
{
  int e = blockIdx.x * blockDim.x + threadIdx.x;
  if (e >= EE) return;
  float s = 0.f;
  for (int r = 0; r < BB; ++r) s += x[r * EE + e];
  float m = s / (float)BB;
  float vs = 0.f;
  for (int r = 0; r < BB; ++r) {
    float d = x[r * EE + e] - m;
    vs = fmaf(d, d, vs);
  }
  float rs = rsqrtf(vs / (float)BB + 1e-5f);
  for (int r = 0; r < BB; ++r) {
    float val = (x[r * EE + e] - m) * rs * g[e] + bta[e];
    y[r * EE + e] = fmaxf(val, 0.f);
  }
}

__global__ __launch_bounds__(256) void topk_norm_kernel(
    const float* __restrict__ gin, float* __restrict__ out)
{
  int b = blockIdx.x, tid = threadIdx.x, lane = tid & 63, wid = tid >> 6;
  __shared__ float vals[512];
  __shared__ float wv[4];
  __shared__ int wi[4];
  __shared__ float sh;
  float g0 = gin[b * 512 + tid];
  float g1 = gin[b * 512 + 256 + tid];
  vals[tid] = g0;
  vals[256 + tid] = g1;
  __syncthreads();
  for (int it = 0; it < 64; ++it) {
    float v = vals[tid];
    int ix = tid;
    float u = vals[256 + tid];
    if (u > v) { v = u; ix = 256 + tid; }
    #pragma unroll
    for (int off = 32; off > 0; off >>= 1) {
      float ov = __shfl_down(v, off);
      int oi = __shfl_down(ix, off);
      if (ov > v || (ov == v && oi < ix)) { v = ov; ix = oi; }
    }
    if (lane == 0) { wv[wid] = v; wi[wid] = ix; }
    __syncthreads();
    if (tid == 0) {
      float bv = wv[0]; int bi = wi[0];
      for (int w = 1; w < 4; ++w)
        if (wv[w] > bv || (wv[w] == bv && wi[w] < bi)) { bv = wv[w]; bi = wi[w]; }
      vals[bi] = -INFINITY;
      sh = bv;
    }
    __syncthreads();
  }
  float thr = sh;
  float m0 = (g0 >= thr) ? g0 : 0.f;
  float m1 = (g1 >= thr) ? g1 : 0.f;
  float ss = m0 * m0 + m1 * m1;
  #pragma unroll
  for (int off = 32; off > 0; off >>= 1) ss += __shfl_down(ss, off);
  if (lane == 0) wv[wid] = ss;
  __syncthreads();
  if (tid == 0) {
    float t = wv[0] + wv[1] + wv[2] + wv[3];
    sh = fmaxf(sqrtf(t), 1e-12f);
  }
  __syncthreads();
  float n = sh;
  out[b * 512 + tid] = m0 / n;
  out[b * 512 + 256 + tid] = m1 / n;
}

// ---------------------------------------------------------------------------
// Host orchestration
// ---------------------------------------------------------------------------
extern "C" void kernel_launch(void* const* d_in, const int* in_sizes, int n_in,
                              void* d_out, int out_size, void* d_ws, size_t ws_size,
                              hipStream_t stream)
{
  const float* tokens  = (const float*)d_in[0];
  const float* centers = (const float*)d_in[1];
  // d_in[2] = lrfs: dead in the reference
  const float* wq      = (const float*)d_in[3];
  const float* wkv     = (const float*)d_in[4];
  const float* mlp_w1  = (const float*)d_in[5];
  const float* mlp_b1  = (const float*)d_in[6];
  const float* mlp_w2  = (const float*)d_in[7];
  const float* mlp_b2  = (const float*)d_in[8];
  const float* bn1_g   = (const float*)d_in[9];
  const float* bn1_b   = (const float*)d_in[10];
  const float* bn2_g   = (const float*)d_in[11];
  const float* bn2_b   = (const float*)d_in[12];
  const float* att_w1  = (const float*)d_in[13];
  const float* att_b1  = (const float*)d_in[14];
  const float* att_w2  = (const float*)d_in[15];
  const float* att_b2  = (const float*)d_in[16];
  const float* emb_w   = (const float*)d_in[17];
  const float* emb_b   = (const float*)d_in[18];
  const float* embn_g  = (const float*)d_in[19];
  const float* embn_b  = (const float*)d_in[20];
  (void)in_sizes; (void)n_in; (void)out_size; (void)ws_size;

  char* ws = (char*)d_ws;
  size_t off = 0;
  auto alloc = [&](size_t bytes) -> void* {
    void* p = ws + off;
    off += (bytes + 255) & ~(size_t)255;
    return p;
  };
  const size_t tokMax  = (size_t)BB * 512 * CC * 4;   // 8 MB
  float* tokA     = (float*)alloc(tokMax);
  float* tokB     = (float*)alloc(tokMax);
  float* ctrA     = (float*)alloc((size_t)BB * 512 * 3 * 4);
  float* ctrB     = (float*)alloc((size_t)BB * 256 * 3 * 4);
  float* ctrC     = (float*)alloc((size_t)BB * 128 * 3 * 4);
  float* tokq_raw = (float*)alloc(tokMax);
  float* Qw1      = (float*)alloc(tokMax);
  float* KVbuf    = (float*)alloc((size_t)BB * 1024 * 512 * 4);  // 32 MB
  float* tq1      = (float*)alloc(tokMax);
  float* mlph     = (float*)alloc((size_t)BB * 512 * 512 * 4);
  float* WFq      = (float*)alloc((size_t)3 * CC * CC * 4);
  float* WFk      = (float*)alloc((size_t)3 * CC * CC * 4);
  __bf16* w2Thi   = (__bf16*)alloc((size_t)3 * CC * CC * 2);
  __bf16* w2Tlo   = (__bf16*)alloc((size_t)3 * CC * CC * 2);
  __bf16* wfqThi  = (__bf16*)alloc((size_t)3 * CC * CC * 2);
  __bf16* wfqTlo  = (__bf16*)alloc((size_t)3 * CC * CC * 2);
  __bf16* wkvThi  = (__bf16*)alloc((size_t)3 * 512 * CC * 2);  // [K|V] rows
  __bf16* wkvTlo  = (__bf16*)alloc((size_t)3 * 512 * CC * 2);
  __bf16* w1Thi   = (__bf16*)alloc((size_t)3 * CC * 512 * 2);
  __bf16* w1Tlo   = (__bf16*)alloc((size_t)3 * CC * 512 * 2);
  __bf16* wm2Thi  = (__bf16*)alloc((size_t)3 * 512 * CC * 2);
  __bf16* wm2Tlo  = (__bf16*)alloc((size_t)3 * 512 * CC * 2);
  int*   rep0     = (int*)alloc((size_t)BB * 512 * 4);
  int*   rep1     = (int*)alloc((size_t)BB * 256 * 4);
  int*   rep2     = (int*)alloc((size_t)BB * 128 * 4);
  int*   nnb      = (int*)alloc((size_t)BB * 512 * 64 * 4);
  float* bnpart   = (float*)alloc((size_t)64 * 512 * 4);
  float* bn1mean  = (float*)alloc(256 * 4);
  float* bn1rstd  = (float*)alloc(256 * 4);
  float* bn2mean  = (float*)alloc(256 * 4);
  float* bn2rstd  = (float*)alloc(256 * 4);
  float* gmeanb   = (float*)alloc((size_t)BB * CC * 4);
  float* gembb    = (float*)alloc((size_t)BB * EE * 4);
  float* grelub   = (float*)alloc((size_t)BB * EE * 4);

  const int NC[3] = {512, 256, 128};
  const int NN[3] = {16, 32, 64};
  int* reps[3] = {rep0, rep1, rep2};
  float* ctrq[3] = {ctrA, ctrB, ctrC};

  // One-time weight prep.
  for (int i = 0; i < 3; ++i) {
    gemm_kernel<<<dim3(4, 4), 256, 0, stream>>>(
        wq + (size_t)i * CC * CC, CC, att_w1 + (size_t)i * CC * CC, CC,
        nullptr, nullptr, WFq + (size_t)i * CC * CC, CC, CC, CC, 0);
    gemm_kernel<<<dim3(4, 4), 256, 0, stream>>>(
        wkv + (size_t)i * CC * 512, 512, att_w1 + (size_t)i * CC * CC, CC,
        nullptr, nullptr, WFk + (size_t)i * CC * CC, CC, CC, CC, 0);
  }
  split_w2_kernel<<<3 * 65536 / 256, 256, 0, stream>>>(att_w2, w2Thi, w2Tlo);
  for (int i = 0; i < 3; ++i) {
    int t1 = CC * CC;
    splitT_kernel<<<(t1 + 255) / 256, 256, 0, stream>>>(
        WFq + (size_t)i * CC * CC, CC, CC, CC,
        wfqThi + (size_t)i * t1, wfqTlo + (size_t)i * t1, t1);
    // merged KV weights [512][256]: rows 0..255 = folded-K, 256..511 = V
    splitT_kernel<<<(t1 + 255) / 256, 256, 0, stream>>>(
        WFk + (size_t)i * CC * CC, CC, CC, CC,
        wkvThi + (size_t)i * 512 * CC, wkvTlo + (size_t)i * 512 * CC, t1);
    splitT_kernel<<<(t1 + 255) / 256, 256, 0, stream>>>(
        wkv + (size_t)i * CC * 512 + CC, 512, CC, CC,
        wkvThi + (size_t)i * 512 * CC + t1, wkvTlo + (size_t)i * 512 * CC + t1, t1);
    int t2 = CC * 512;   // mlp_w1: K=256, N=512
    splitT_kernel<<<(t2 + 255) / 256, 256, 0, stream>>>(
        mlp_w1 + (size_t)i * t2, 512, CC, 512,
        w1Thi + (size_t)i * t2, w1Tlo + (size_t)i * t2, t2);
    // mlp_w2: K=512, N=256
    splitT_kernel<<<(t2 + 255) / 256, 256, 0, stream>>>(
        mlp_w2 + (size_t)i * t2, CC, 512, CC,
        wm2Thi + (size_t)i * t2, wm2Tlo + (size_t)i * t2, t2);
  }

  const float* cur_tok = tokens;
  const float* cur_ctr = centers;
  int curTt = TT0;
  float* tok_bufs[2] = {tokA, tokB};

  // fps0 (on raw centers) is co-scheduled with the stage-0 KV projection.
  for (int i = 0; i < 3; ++i) {
    int Tq = NC[i], Kn = NN[i], Tt = curTt;
    float* ctr_q = ctrq[i];
    float* tok_next = tok_bufs[i & 1];
    int M = BB * Tq;
    int Mt = BB * Tt;
    int* rep = reps[i];

    const float *b1m = nullptr, *b1r = nullptr, *b1g = nullptr, *b1b = nullptr;

    if (i == 0) {
      // KV0 projection (A=tokens, no BN) + co-scheduled fps0
      gemm_mfma_kernel<16><<<dim3(512 / 64 + 1, Mt / 128), 256, 0, stream>>>(
          tokens, CC, wkvThi, wkvTlo, nullptr, nullptr, KVbuf,
          Mt, 512, CC, 0, nullptr, nullptr, nullptr, nullptr,
          512 / 64, centers, 1024, 512, rep0);
    }

    // gathers (need rep_i) + kNN (wave-private, barrier-free)
    {
      int tot = BB * Tq * 3;
      gather_rows_kernel<<<(tot + 255) / 256, 256, 0, stream>>>(
          cur_ctr, rep, ctr_q, Tq, Tt, 3, tot);
    }
    {
      int tot = M * CC;
      gather_rows_kernel<<<(tot + 255) / 256, 256, 0, stream>>>(
          cur_tok, rep, tokq_raw, Tq, Tt, CC, tot);
    }
    if (Tt == 1024)
      knn_wave_kernel<16><<<M / 4, 256, 0, stream>>>(ctr_q, cur_ctr, Tq, Tt, Kn, nnb);
    else if (Tt == 512)
      knn_wave_kernel<8><<<M / 4, 256, 0, stream>>>(ctr_q, cur_ctr, Tq, Tt, Kn, nnb);
    else
      knn_wave_kernel<4><<<M / 4, 256, 0, stream>>>(ctr_q, cur_ctr, Tq, Tt, Kn, nnb);

    if (i > 0) {
      // BN1 stats over concat(query, target); apply fused into GEMMs
      bn_stats_kernel<<<64, 256, 0, stream>>>(tokq_raw, M, cur_tok, Mt, bnpart, 64);
      bn_finalize_kernel<<<1, 256, 0, stream>>>(bnpart, 64, M + Mt, bn1mean, bn1rstd);
      b1m = bn1mean; b1r = bn1rstd; b1g = bn1_g + i * CC; b1b = bn1_b + i * CC;
      // KV projection with fused BN1; stage 1 also co-schedules fps2 (ctrB
      // is ready from this stage's center gather).
      if (i == 1)
        gemm_mfma_kernel<4><<<dim3(512 / 64 + 1, Mt / 128), 256, 0, stream>>>(
            cur_tok, CC, wkvThi + (size_t)i * 512 * CC, wkvTlo + (size_t)i * 512 * CC,
            nullptr, nullptr, KVbuf, Mt, 512, CC, 0, b1m, b1r, b1g, b1b,
            512 / 64, ctrB, 256, 128, rep2);
      else
        gemm_mfma_kernel<4><<<dim3(512 / 64, Mt / 128), 256, 0, stream>>>(
            cur_tok, CC, wkvThi + (size_t)i * 512 * CC, wkvTlo + (size_t)i * 512 * CC,
            nullptr, nullptr, KVbuf, Mt, 512, CC, 0, b1m, b1r, b1g, b1b,
            512 / 64, nullptr, 0, 0, nullptr);
    }

    // Q projection (folded weights, fused BN1)
    gemm_mfma_kernel<4><<<dim3(CC / 64, M / 128), 256, 0, stream>>>(
        tokq_raw, CC, wfqThi + (size_t)i * CC * CC, wfqTlo + (size_t)i * CC * CC,
        nullptr, nullptr, Qw1, M, CC, CC, 0, b1m, b1r, b1g, b1b,
        CC / 64, nullptr, 0, 0, nullptr);

    // Fused neighborhood attention via MFMA, 128 rows/block (+ skip)
    if (Kn == 16)
      attn5_kernel<16><<<dim3(M / 8), 256, 0, stream>>>(
          Qw1, KVbuf, nnb, att_b1 + i * CC,
          w2Thi + (size_t)i * CC * CC, w2Tlo + (size_t)i * CC * CC,
          att_b2 + i * CC, tokq_raw, tq1, Tq, Tt);
    else if (Kn == 32)
      attn5_kernel<32><<<dim3(M / 4), 256, 0, stream>>>(
          Qw1, KVbuf, nnb, att_b1 + i * CC,
          w2Thi + (size_t)i * CC * CC, w2Tlo + (size_t)i * CC * CC,
          att_b2 + i * CC, tokq_raw, tq1, Tq, Tt);
    else
      attn5_kernel<64><<<dim3(M / 2), 256, 0, stream>>>(
          Qw1, KVbuf, nnb, att_b1 + i * CC,
          w2Thi + (size_t)i * CC * CC, w2Tlo + (size_t)i * CC * CC,
          att_b2 + i * CC, tokq_raw, tq1, Tq, Tt);

    // BN2 stats + MLP (+ skip2); BN2 fused into MLP1. Stage 0's MLP1 also
    // co-schedules fps1 (ctrA ready from this stage's center gather).
    bn_stats_kernel<<<64, 256, 0, stream>>>(tq1, M, tq1, 0, bnpart, 64);
    bn_finalize_kernel<<<1, 256, 0, stream>>>(bnpart, 64, M, bn2mean, bn2rstd);
    if (i == 0)
      gemm_mfma_kernel<8><<<dim3(512 / 64 + 1, M / 128), 256, 0, stream>>>(
          tq1, CC, w1Thi + (size_t)i * CC * 512, w1Tlo + (size_t)i * CC * 512,
          mlp_b1 + i * 512, nullptr, mlph, M, 512, CC, 1,
          bn2mean, bn2rstd, bn2_g + i * CC, bn2_b + i * CC,
          512 / 64, ctrA, 512, 256, rep1);
    else
      gemm_mfma_kernel<4><<<dim3(512 / 64, M / 128), 256, 0, stream>>>(
          tq1, CC, w1Thi + (size_t)i * CC * 512, w1Tlo + (size_t)i * CC * 512,
          mlp_b1 + i * 512, nullptr, mlph, M, 512, CC, 1,
          bn2mean, bn2rstd, bn2_g + i * CC, bn2_b + i * CC,
          512 / 64, nullptr, 0, 0, nullptr);
    gemm_mfma_kernel<4><<<dim3(CC / 64, M / 128), 256, 0, stream>>>(
        mlph, 512, wm2Thi + (size_t)i * 512 * CC, wm2Tlo + (size_t)i * 512 * CC,
        mlp_b2 + i * CC, tq1, tok_next, M, CC, 512, 0,
        nullptr, nullptr, nullptr, nullptr,
        CC / 64, nullptr, 0, 0, nullptr);

    cur_tok = tok_next;
    cur_ctr = ctr_q;
    curTt = Tq;
  }

  // Final head
  gmean_kernel<<<(BB * CC + 255) / 256, 256, 0, stream>>>(cur_tok, gmeanb, curTt);
  gemm_kernel<<<dim3(EE / 64, 1), 256, 0, stream>>>(
      gmeanb, CC, emb_w, EE, emb_b, nullptr, gembb, BB, EE, CC, 0);
  embbn_kernel<<<2, 256, 0, stream>>>(gembb, embn_g, embn_b, grelub);
  topk_norm_kernel<<<BB, 256, 0, stream>>>(grelub, (float*)d_out);
}